// Round 8
// baseline (231.596 us; speedup 1.0000x reference)
//
#include <hip/hip_runtime.h>
#include <math.h>

#define NQc 40000
#define Wc 200
#define Hc 200

typedef __attribute__((ext_vector_type(8))) short short8;
typedef __attribute__((ext_vector_type(4))) float f32x4;
typedef __attribute__((ext_vector_type(2))) float f32x2;

// counted vmem wait: lets prefetch loads stay in flight across barriers
#define VMWAIT(N) asm volatile("s_waitcnt vmcnt(" #N ")" ::: "memory")

__device__ __forceinline__ ushort f2b(float f) {
  unsigned u = __float_as_uint(f);
  u = (u + 0x7fffu + ((u >> 16) & 1u)) >> 16;
  return (ushort)u;
}

// async global->LDS, 16B per lane; LDS dest is wave-uniform base + lane*16
__device__ __forceinline__ void glds16(const void* g, void* l) {
  __builtin_amdgcn_global_load_lds(
      (const __attribute__((address_space(1))) void*)g,
      (__attribute__((address_space(3))) void*)l, 16, 0, 0);
}

// ---------------------------------------------------------------------------
// prep_all: blocks [0,5000): single-pass qlo = bf16(q), qhi = bf16(q+qp) for
// the SAME 8 columns per thread (q read once). blocks [5000,5896): weights.
// ---------------------------------------------------------------------------
__global__ __launch_bounds__(256) void prep_all(
    const float* __restrict__ q, const float* __restrict__ qp,
    const float* __restrict__ Wv, const float* __restrict__ Wo,
    const float* __restrict__ Wso, const float* __restrict__ Waw,
    ushort* __restrict__ qlo, ushort* __restrict__ qhi,
    ushort* __restrict__ WvT, ushort* __restrict__ WoT,
    ushort* __restrict__ WsoT, ushort* __restrict__ WawT) {
  const int bid = blockIdx.x;
  if (bid < 5000) {
    const int flat = bid * 256 + threadIdx.x;   // 1.28M threads, 8 cols each
    const int m = flat >> 5;
    const int c8 = (flat & 31) * 8;
    const float4 a  = *(const float4*)(q  + (size_t)m * 256 + c8);
    const float4 b  = *(const float4*)(q  + (size_t)m * 256 + c8 + 4);
    const float4 ap = *(const float4*)(qp + (size_t)m * 256 + c8);
    const float4 bp = *(const float4*)(qp + (size_t)m * 256 + c8 + 4);
    ushort lo[8], hi[8];
    lo[0] = f2b(a.x); lo[1] = f2b(a.y); lo[2] = f2b(a.z); lo[3] = f2b(a.w);
    lo[4] = f2b(b.x); lo[5] = f2b(b.y); lo[6] = f2b(b.z); lo[7] = f2b(b.w);
    hi[0] = f2b(a.x + ap.x); hi[1] = f2b(a.y + ap.y);
    hi[2] = f2b(a.z + ap.z); hi[3] = f2b(a.w + ap.w);
    hi[4] = f2b(b.x + bp.x); hi[5] = f2b(b.y + bp.y);
    hi[6] = f2b(b.z + bp.z); hi[7] = f2b(b.w + bp.w);
    *(uint4*)&qlo[(size_t)m * 256 + c8] = *(const uint4*)lo;
    *(uint4*)&qhi[(size_t)m * 256 + c8] = *(const uint4*)hi;
  } else {
    const int idx = (bid - 5000) * 256 + threadIdx.x;
    if (idx < 65536) {
      int n = idx >> 8, k = idx & 255;
      WvT[idx] = f2b(Wv[k * 256 + n]);
    } else if (idx < 131072) {
      int i = idx - 65536;
      int n = i >> 8, k = i & 255;
      WoT[i] = f2b(Wo[k * 256 + n]);
    } else if (idx < 196608) {
      int i = idx - 131072;
      int n = i >> 9, k = i & 511;
      WsoT[i] = f2b(Wso[k * 128 + n]);
    } else {
      int i = idx - 196608;
      int n = i >> 9, k = i & 511;
      WawT[i] = f2b(Waw[k * 64 + n]);
    }
  }
}

// ---------------------------------------------------------------------------
// Swizzle convention for unpadded LDS tiles (64 ushorts = 8 chunks of 16B/row):
// LDS slot (row, c) holds global 16B-chunk (c ^ (row & 7)). glds writes are
// lane-contiguous (base + lane*16); ds_read_b128 spreads banks 2-way max.
//
// K-loops: counted-vmcnt 2-deep pipeline (catalog T3+T4). Per step:
//   STAGE(t+1) -> s_waitcnt vmcnt(L) -> s_barrier -> MFMA(buf cur) -> s_barrier
// vmcnt never drains to 0 inside the loop; only glds16 touches vmem in-loop.
// ---------------------------------------------------------------------------

// [so|aw] = [qlo | qhi] @ [WsoT(128)|WawT(64)]^T, N=192, K=512, BM=64.
__global__ __launch_bounds__(256, 2) void gemm_soaw_k(
    const ushort* __restrict__ qlo, const ushort* __restrict__ qhi,
    const ushort* __restrict__ WsoT, const ushort* __restrict__ WawT,
    const float* __restrict__ b_so, const float* __restrict__ b_aw,
    float* __restrict__ so_ws, float* __restrict__ aw_ws) {
  __shared__ __align__(16) char smem[65536];
  float (*E)[68] = (float(*)[68])smem;
  f32x4 acc[12] = {};
  const int m0 = blockIdx.x * 64;
  const int tid = threadIdx.x;
  const int w = tid >> 6, lane = tid & 63;
  const int rl = lane & 15, q2 = lane >> 4;
  const int sw8 = rl & 7;
  const int lrow = lane >> 3, lch = (lane & 7) ^ (lrow & 7);

  auto STAGE = [&](int buf, int t) {
    ushort* As = (ushort*)(smem + buf * 32768);
    ushort* Bs = As + 4096;
    const int k0 = t * 64;
    const ushort* aq = (k0 < 256) ? qlo : qhi;
    const int ka = k0 & 255;
#pragma unroll
    for (int i = 0; i < 2; ++i) {
      const int g = w * 2 + i;
      const int row = g * 8 + lrow;
      glds16(aq + (size_t)(m0 + row) * 256 + ka + lch * 8,
             As + g * 512 + lane * 8);
    }
#pragma unroll
    for (int i = 0; i < 6; ++i) {
      const int g = w * 6 + i;
      const int row = g * 8 + lrow;
      const ushort* gsrc = (row < 128)
          ? WsoT + (size_t)row * 512 + k0 + lch * 8
          : WawT + (size_t)(row - 128) * 512 + k0 + lch * 8;
      glds16(gsrc, Bs + g * 512 + lane * 8);
    }
  };

  STAGE(0, 0);
#pragma unroll
  for (int t = 0; t < 8; ++t) {
    const int cur = t & 1;
    if (t < 7) { STAGE(cur ^ 1, t + 1); VMWAIT(8); }
    else       { VMWAIT(0); }
    __builtin_amdgcn_s_barrier();
    {
      const ushort* Asb = (const ushort*)(smem + cur * 32768);
      const ushort* Bsb = Asb + 4096;
#pragma unroll
      for (int kk = 0; kk < 2; ++kk) {
        const short8 af = *(const short8*)
            &Asb[(w * 16 + rl) * 64 + ((kk * 4 + q2) ^ sw8) * 8];
#pragma unroll
        for (int nj = 0; nj < 12; ++nj) {
          const short8 bf = *(const short8*)
              &Bsb[(nj * 16 + rl) * 64 + ((kk * 4 + q2) ^ sw8) * 8];
          acc[nj] = __builtin_amdgcn_mfma_f32_16x16x32_bf16(af, bf, acc[nj], 0, 0, 0);
        }
      }
    }
    __builtin_amdgcn_s_barrier();
  }

  const int rbase = q2 * 4, cl = rl;
#pragma unroll
  for (int p = 0; p < 3; ++p) {
#pragma unroll
    for (int j = 0; j < 4; ++j) {
      const int nj = p * 4 + j;
      const int nl = j * 16 + cl;
      const f32x4 a = acc[nj];
      if (p < 2) {
        const float bb = b_so[p * 64 + nl];
#pragma unroll
        for (int r = 0; r < 4; ++r)
          E[w * 16 + rbase + r][nl] = a[r] + bb;
      } else {
        const float bb = b_aw[nl];
#pragma unroll
        for (int r = 0; r < 4; ++r) {
          float z = a[r] + bb;
          float zm = fmaxf(z, __shfl_xor(z, 1, 64));
          zm = fmaxf(zm, __shfl_xor(zm, 2, 64));
          float e = expf(z - zm);
          float s = e + __shfl_xor(e, 1, 64);
          s = s + __shfl_xor(s, 2, 64);
          E[w * 16 + rbase + r][nl] = e / s;
        }
      }
    }
    __syncthreads();
#pragma unroll
    for (int it = 0; it < 4; ++it) {
      const int flat = it * 256 + tid;
      const int row = flat >> 4, c4 = (flat & 15) * 4;
      const float4 vle = *(const float4*)&E[row][c4];
      if (p < 2)
        *(float4*)&so_ws[(size_t)(m0 + row) * 128 + p * 64 + c4] = vle;
      else
        *(float4*)&aw_ws[(size_t)(m0 + row) * 64 + c4] = vle;
    }
    __syncthreads();
  }
}

// v = qlo @ WvT + b_v -> bf16 head-major vt (NH, NQ, 32). N=128/block, K=256.
__global__ __launch_bounds__(256, 3) void gemm_v_k(
    const ushort* __restrict__ qlo, const ushort* __restrict__ WvT,
    const float* __restrict__ bv, ushort* __restrict__ vt) {
  __shared__ __align__(16) char smem[49152];
  ushort (*Eb)[72] = (ushort(*)[72])smem;
  f32x4 acc[8] = {};
  const int m0 = blockIdx.x * 64, n0 = blockIdx.y * 128;
  const int tid = threadIdx.x;
  const int w = tid >> 6, lane = tid & 63;
  const int rl = lane & 15, q2 = lane >> 4;
  const int sw8 = rl & 7;
  const int lrow = lane >> 3, lch = (lane & 7) ^ (lrow & 7);

  auto STAGE = [&](int buf, int t) {
    ushort* As = (ushort*)(smem + buf * 24576);
    ushort* Bs = As + 4096;
    const int k0 = t * 64;
#pragma unroll
    for (int i = 0; i < 2; ++i) {
      const int g = w * 2 + i;
      const int row = g * 8 + lrow;
      glds16(qlo + (size_t)(m0 + row) * 256 + k0 + lch * 8,
             As + g * 512 + lane * 8);
    }
#pragma unroll
    for (int i = 0; i < 4; ++i) {
      const int g = w * 4 + i;
      const int row = g * 8 + lrow;
      glds16(WvT + (size_t)(n0 + row) * 256 + k0 + lch * 8,
             Bs + g * 512 + lane * 8);
    }
  };

  STAGE(0, 0);
#pragma unroll
  for (int t = 0; t < 4; ++t) {
    const int cur = t & 1;
    if (t < 3) { STAGE(cur ^ 1, t + 1); VMWAIT(6); }
    else       { VMWAIT(0); }
    __builtin_amdgcn_s_barrier();
    {
      const ushort* Asb = (const ushort*)(smem + cur * 24576);
      const ushort* Bsb = Asb + 4096;
#pragma unroll
      for (int kk = 0; kk < 2; ++kk) {
        const short8 af = *(const short8*)
            &Asb[(w * 16 + rl) * 64 + ((kk * 4 + q2) ^ sw8) * 8];
#pragma unroll
        for (int nj = 0; nj < 8; ++nj) {
          const short8 bf = *(const short8*)
              &Bsb[(nj * 16 + rl) * 64 + ((kk * 4 + q2) ^ sw8) * 8];
          acc[nj] = __builtin_amdgcn_mfma_f32_16x16x32_bf16(af, bf, acc[nj], 0, 0, 0);
        }
      }
    }
    __builtin_amdgcn_s_barrier();
  }

  const int rbase = q2 * 4, cl = rl;
#pragma unroll
  for (int p = 0; p < 2; ++p) {
#pragma unroll
    for (int j = 0; j < 4; ++j) {
      const int nj = p * 4 + j;
      const int n = n0 + p * 64 + j * 16 + cl;
      const float bb = bv[n];
      const f32x4 a = acc[nj];
#pragma unroll
      for (int r = 0; r < 4; ++r)
        Eb[w * 16 + rbase + r][j * 16 + cl] = f2b(a[r] + bb);
    }
    __syncthreads();
#pragma unroll
    for (int hh = 0; hh < 2; ++hh) {
      const int h = (n0 + p * 64) / 32 + hh;
#pragma unroll
      for (int it = 0; it < 2; ++it) {
        const int flat = it * 256 + tid;
        const int row = flat >> 3, d4 = (flat & 7) * 4;
        *(ushort4*)&vt[((size_t)h * NQc + m0 + row) * 32 + d4] =
            *(const ushort4*)&Eb[row][hh * 32 + d4];
      }
    }
    __syncthreads();
  }
}

// ---------------------------------------------------------------------------
// gemm_front: soaw + v merged into ONE launch (used only when workspace
// permits non-aliased vt). bid<1250: v path; bid>=1250: soaw path.
// ---------------------------------------------------------------------------
__global__ __launch_bounds__(256, 2) void gemm_front(
    const ushort* __restrict__ qlo, const ushort* __restrict__ qhi,
    const ushort* __restrict__ WvT, const ushort* __restrict__ WsoT,
    const ushort* __restrict__ WawT,
    const float* __restrict__ bv, const float* __restrict__ b_so,
    const float* __restrict__ b_aw,
    ushort* __restrict__ vt, float* __restrict__ so_ws,
    float* __restrict__ aw_ws) {
  __shared__ __align__(16) char smem[65536];
  const int tid = threadIdx.x;
  const int w = tid >> 6, lane = tid & 63;
  const int rl = lane & 15, q2 = lane >> 4;
  const int sw8 = rl & 7;
  const int lrow = lane >> 3, lch = (lane & 7) ^ (lrow & 7);
  const int bid = blockIdx.x;

  if (bid < 1250) {
    // ================= v path =================
    ushort (*Eb)[72] = (ushort(*)[72])smem;
    f32x4 acc[8] = {};
    const int m0 = (bid >> 1) * 64, n0 = (bid & 1) * 128;

    auto STAGE = [&](int buf, int t) {
      ushort* As = (ushort*)(smem + buf * 24576);
      ushort* Bs = As + 4096;
      const int k0 = t * 64;
#pragma unroll
      for (int i = 0; i < 2; ++i) {
        const int g = w * 2 + i;
        const int row = g * 8 + lrow;
        glds16(qlo + (size_t)(m0 + row) * 256 + k0 + lch * 8,
               As + g * 512 + lane * 8);
      }
#pragma unroll
      for (int i = 0; i < 4; ++i) {
        const int g = w * 4 + i;
        const int row = g * 8 + lrow;
        glds16(WvT + (size_t)(n0 + row) * 256 + k0 + lch * 8,
               Bs + g * 512 + lane * 8);
      }
    };

    STAGE(0, 0);
#pragma unroll
    for (int t = 0; t < 4; ++t) {
      const int cur = t & 1;
      if (t < 3) { STAGE(cur ^ 1, t + 1); VMWAIT(6); }
      else       { VMWAIT(0); }
      __builtin_amdgcn_s_barrier();
      {
        const ushort* Asb = (const ushort*)(smem + cur * 24576);
        const ushort* Bsb = Asb + 4096;
#pragma unroll
        for (int kk = 0; kk < 2; ++kk) {
          const short8 af = *(const short8*)
              &Asb[(w * 16 + rl) * 64 + ((kk * 4 + q2) ^ sw8) * 8];
#pragma unroll
          for (int nj = 0; nj < 8; ++nj) {
            const short8 bf = *(const short8*)
                &Bsb[(nj * 16 + rl) * 64 + ((kk * 4 + q2) ^ sw8) * 8];
            acc[nj] = __builtin_amdgcn_mfma_f32_16x16x32_bf16(af, bf, acc[nj], 0, 0, 0);
          }
        }
      }
      __builtin_amdgcn_s_barrier();
    }

    const int rbase = q2 * 4, cl = rl;
#pragma unroll
    for (int p = 0; p < 2; ++p) {
#pragma unroll
      for (int j = 0; j < 4; ++j) {
        const int nj = p * 4 + j;
        const int n = n0 + p * 64 + j * 16 + cl;
        const float bb = bv[n];
        const f32x4 a = acc[nj];
#pragma unroll
        for (int r = 0; r < 4; ++r)
          Eb[w * 16 + rbase + r][j * 16 + cl] = f2b(a[r] + bb);
      }
      __syncthreads();
#pragma unroll
      for (int hh = 0; hh < 2; ++hh) {
        const int h = (n0 + p * 64) / 32 + hh;
#pragma unroll
        for (int it = 0; it < 2; ++it) {
          const int flat = it * 256 + tid;
          const int row = flat >> 3, d4 = (flat & 7) * 4;
          *(ushort4*)&vt[((size_t)h * NQc + m0 + row) * 32 + d4] =
              *(const ushort4*)&Eb[row][hh * 32 + d4];
        }
      }
      __syncthreads();
    }
  } else {
    // ================= soaw path =================
    float (*E)[68] = (float(*)[68])smem;
    f32x4 acc[12] = {};
    const int m0 = (bid - 1250) * 64;

    auto STAGE = [&](int buf, int t) {
      ushort* As = (ushort*)(smem + buf * 32768);
      ushort* Bs = As + 4096;
      const int k0 = t * 64;
      const ushort* aq = (k0 < 256) ? qlo : qhi;
      const int ka = k0 & 255;
#pragma unroll
      for (int i = 0; i < 2; ++i) {
        const int g = w * 2 + i;
        const int row = g * 8 + lrow;
        glds16(aq + (size_t)(m0 + row) * 256 + ka + lch * 8,
               As + g * 512 + lane * 8);
      }
#pragma unroll
      for (int i = 0; i < 6; ++i) {
        const int g = w * 6 + i;
        const int row = g * 8 + lrow;
        const ushort* gsrc = (row < 128)
            ? WsoT + (size_t)row * 512 + k0 + lch * 8
            : WawT + (size_t)(row - 128) * 512 + k0 + lch * 8;
        glds16(gsrc, Bs + g * 512 + lane * 8);
      }
    };

    STAGE(0, 0);
#pragma unroll
    for (int t = 0; t < 8; ++t) {
      const int cur = t & 1;
      if (t < 7) { STAGE(cur ^ 1, t + 1); VMWAIT(8); }
      else       { VMWAIT(0); }
      __builtin_amdgcn_s_barrier();
      {
        const ushort* Asb = (const ushort*)(smem + cur * 32768);
        const ushort* Bsb = Asb + 4096;
#pragma unroll
        for (int kk = 0; kk < 2; ++kk) {
          const short8 af = *(const short8*)
              &Asb[(w * 16 + rl) * 64 + ((kk * 4 + q2) ^ sw8) * 8];
#pragma unroll
          for (int nj = 0; nj < 12; ++nj) {
            const short8 bf = *(const short8*)
                &Bsb[(nj * 16 + rl) * 64 + ((kk * 4 + q2) ^ sw8) * 8];
            acc[nj] = __builtin_amdgcn_mfma_f32_16x16x32_bf16(af, bf, acc[nj], 0, 0, 0);
          }
        }
      }
      __builtin_amdgcn_s_barrier();
    }

    const int rbase = q2 * 4, cl = rl;
#pragma unroll
    for (int p = 0; p < 3; ++p) {
#pragma unroll
      for (int j = 0; j < 4; ++j) {
        const int nj = p * 4 + j;
        const int nl = j * 16 + cl;
        const f32x4 a = acc[nj];
        if (p < 2) {
          const float bb = b_so[p * 64 + nl];
#pragma unroll
          for (int r = 0; r < 4; ++r)
            E[w * 16 + rbase + r][nl] = a[r] + bb;
        } else {
          const float bb = b_aw[nl];
#pragma unroll
          for (int r = 0; r < 4; ++r) {
            float z = a[r] + bb;
            float zm = fmaxf(z, __shfl_xor(z, 1, 64));
            zm = fmaxf(zm, __shfl_xor(zm, 2, 64));
            float e = expf(z - zm);
            float s = e + __shfl_xor(e, 1, 64);
            s = s + __shfl_xor(s, 2, 64);
            E[w * 16 + rbase + r][nl] = e / s;
          }
        }
      }
      __syncthreads();
#pragma unroll
      for (int it = 0; it < 4; ++it) {
        const int flat = it * 256 + tid;
        const int row = flat >> 4, c4 = (flat & 15) * 4;
        const float4 vle = *(const float4*)&E[row][c4];
        if (p < 2)
          *(float4*)&so_ws[(size_t)(m0 + row) * 128 + p * 64 + c4] = vle;
        else
          *(float4*)&aw_ws[(size_t)(m0 + row) * 64 + c4] = vle;
      }
      __syncthreads();
    }
  }
}

// out = out_pre @ WoT + b_o -> fp32. N=128/block, K=256. Counted-vmcnt dbuf.
__global__ __launch_bounds__(256, 3) void gemm_o_k(
    const ushort* __restrict__ Ap, const ushort* __restrict__ WoT,
    const float* __restrict__ bo, float* __restrict__ out) {
  __shared__ __align__(16) char smem[49152];
  float (*E)[68] = (float(*)[68])smem;
  f32x4 acc[8] = {};
  const int m0 = blockIdx.x * 64, n0 = blockIdx.y * 128;
  const int tid = threadIdx.x;
  const int w = tid >> 6, lane = tid & 63;
  const int rl = lane & 15, q2 = lane >> 4;
  const int sw8 = rl & 7;
  const int lrow = lane >> 3, lch = (lane & 7) ^ (lrow & 7);

  auto STAGE = [&](int buf, int t) {
    ushort* As = (ushort*)(smem + buf * 24576);
    ushort* Bs = As + 4096;
    const int k0 = t * 64;
#pragma unroll
    for (int i = 0; i < 2; ++i) {
      const int g = w * 2 + i;
      const int row = g * 8 + lrow;
      glds16(Ap + (size_t)(m0 + row) * 256 + k0 + lch * 8,
             As + g * 512 + lane * 8);
    }
#pragma unroll
    for (int i = 0; i < 4; ++i) {
      const int g = w * 4 + i;
      const int row = g * 8 + lrow;
      glds16(WoT + (size_t)(n0 + row) * 256 + k0 + lch * 8,
             Bs + g * 512 + lane * 8);
    }
  };

  STAGE(0, 0);
#pragma unroll
  for (int t = 0; t < 4; ++t) {
    const int cur = t & 1;
    if (t < 3) { STAGE(cur ^ 1, t + 1); VMWAIT(6); }
    else       { VMWAIT(0); }
    __builtin_amdgcn_s_barrier();
    {
      const ushort* Asb = (const ushort*)(smem + cur * 24576);
      const ushort* Bsb = Asb + 4096;
#pragma unroll
      for (int kk = 0; kk < 2; ++kk) {
        const short8 af = *(const short8*)
            &Asb[(w * 16 + rl) * 64 + ((kk * 4 + q2) ^ sw8) * 8];
#pragma unroll
        for (int nj = 0; nj < 8; ++nj) {
          const short8 bf = *(const short8*)
              &Bsb[(nj * 16 + rl) * 64 + ((kk * 4 + q2) ^ sw8) * 8];
          acc[nj] = __builtin_amdgcn_mfma_f32_16x16x32_bf16(af, bf, acc[nj], 0, 0, 0);
        }
      }
    }
    __builtin_amdgcn_s_barrier();
  }

  const int rbase = q2 * 4, cl = rl;
#pragma unroll
  for (int p = 0; p < 2; ++p) {
#pragma unroll
    for (int j = 0; j < 4; ++j) {
      const int nj = p * 4 + j;
      const int n = n0 + p * 64 + j * 16 + cl;
      const float bb = bo[n];
      const f32x4 a = acc[nj];
#pragma unroll
      for (int r = 0; r < 4; ++r)
        E[w * 16 + rbase + r][j * 16 + cl] = a[r] + bb;
    }
    __syncthreads();
#pragma unroll
    for (int it = 0; it < 4; ++it) {
      const int flat = it * 256 + tid;
      const int row = flat >> 4, c4 = (flat & 15) * 4;
      *(float4*)&out[(size_t)(m0 + row) * 256 + n0 + p * 64 + c4] =
          *(const float4*)&E[row][c4];
    }
    __syncthreads();
  }
}

// ---------------------------------------------------------------------------
// Deformable sampling v5: block = one head x 32 queries; head = blockIdx.x & 7
// pins each head's 2.56 MB vt slice to one XCD's L2.
//
// Gather via glds16 into a per-wave LDS buffer with counted vmcnt: each thread
// issues 8 16B tap-loads per half (j 0..3, then 4..7), always 8 in flight,
// consumed j-by-j at vmcnt(6/4/2/0). Zero VGPR for in-flight data; waves are
// self-contained (8 queries/wave) so phase 2 has NO barriers. LDS ~39.7KB ->
// 4 blocks/CU; in-flight bytes/CU ~4x the reg-burst version -> covers XCD-L2
// latency. Consume math (weights, unpack, pk-fma, shfl combine) unchanged.
// ---------------------------------------------------------------------------
__global__ __launch_bounds__(256) void sample_kernel(
    const ushort* __restrict__ vt,    // (NH, NQ, 32) bf16
    const float* __restrict__ so_ws,  // (NQ, 128)
    const float* __restrict__ aw_ws,  // (NQ, 64)
    const float* __restrict__ refp,   // (NQ, 2)
    ushort* __restrict__ out_pre)     // (NQ, 256) bf16
{
  __shared__ __align__(16) char gbuf[32768];  // 4 waves x 8 chunks x 1KB
  __shared__ int2   offs[32][9];
  __shared__ float2 wts2[32][9][2];
  const int h  = blockIdx.x & 7;
  const int m0 = (blockIdx.x >> 3) * 32;
  const int tid = threadIdx.x;

  {
    const int j  = tid & 7;
    const int qi = tid >> 3;
    const int m  = m0 + qi;
    const int c  = h * 8 + j;
    const float sx  = so_ws[(size_t)m * 128 + c * 2 + 0];
    const float sy  = so_ws[(size_t)m * 128 + c * 2 + 1];
    const float wgt = 0.5f * aw_ws[(size_t)m * 64 + c];
    const float x = refp[m * 2 + 0] * (float)Wc + sx - 0.5f;
    const float y = refp[m * 2 + 1] * (float)Hc + sy - 0.5f;
    const float x0f = floorf(x), y0f = floorf(y);
    const int x0 = (int)x0f, y0 = (int)y0f;
    const int x1 = x0 + 1, y1 = y0 + 1;
    const float wx1 = x - x0f, wx0 = 1.0f - wx1;
    const float wy1 = y - y0f, wy0 = 1.0f - wy1;
    const float wx0v = (x0 >= 0 && x0 < Wc) ? wx0 : 0.0f;
    const float wx1v = (x1 >= 0 && x1 < Wc) ? wx1 : 0.0f;
    const float wy0v = ((y0 >= 0 && y0 < Hc) ? wy0 : 0.0f) * wgt;
    const float wy1v = ((y1 >= 0 && y1 < Hc) ? wy1 : 0.0f) * wgt;
    const int bx = min(max(x0, 0), Wc - 2);
    const float wl = (bx == x0) ? wx0v : ((bx == x1) ? wx1v : 0.0f);
    const float wr = (bx + 1 == x1) ? wx1v : ((bx + 1 == x0) ? wx0v : 0.0f);
    const int cy0 = min(max(y0, 0), Hc - 1);
    const int cy1 = min(max(y1, 0), Hc - 1);
    offs[qi][j] = make_int2((cy0 * Wc + bx) * 64, (cy1 * Wc + bx) * 64);
    wts2[qi][j][0] = make_float2(wl * wy0v, wl * wy1v);
    wts2[qi][j][1] = make_float2(wr * wy0v, wr * wy1v);
  }
  __syncthreads();

  const int qi = tid >> 3;
  const int ld = tid & 7;
  const int w  = tid >> 6;
  const int m  = m0 + qi;
  const int hf = ld >> 2;
  const char* __restrict__ vb =
      (const char*)(vt + (size_t)h * NQc * 32) + (uint)(ld * 16);
  char* Gw = gbuf + w * 8192;                 // wave-private gather region
  const int qo = (qi & 7) * 128 + ld * 16;    // consume offset within chunk

  f32x2 acc0 = {0.0f, 0.0f}, acc1 = {0.0f, 0.0f};
  f32x2 acc2 = {0.0f, 0.0f}, acc3 = {0.0f, 0.0f};

  auto acc16 = [&](uint4 rawv, float wsc) {
    const f32x2 wv = {wsc, wsc};
    f32x2 v0, v1, v2, v3;
    v0.x = __uint_as_float(rawv.x << 16);
    v0.y = __uint_as_float(rawv.x & 0xFFFF0000u);
    v1.x = __uint_as_float(rawv.y << 16);
    v1.y = __uint_as_float(rawv.y & 0xFFFF0000u);
    v2.x = __uint_as_float(rawv.z << 16);
    v2.y = __uint_as_float(rawv.z & 0xFFFF0000u);
    v3.x = __uint_as_float(rawv.w << 16);
    v3.y = __uint_as_float(rawv.w & 0xFFFF0000u);
#if __has_builtin(__builtin_elementwise_fma)
    acc0 = __builtin_elementwise_fma(wv, v0, acc0);
    acc1 = __builtin_elementwise_fma(wv, v1, acc1);
    acc2 = __builtin_elementwise_fma(wv, v2, acc2);
    acc3 = __builtin_elementwise_fma(wv, v3, acc3);
#else
    acc0.x = fmaf(wsc, v0.x, acc0.x); acc0.y = fmaf(wsc, v0.y, acc0.y);
    acc1.x = fmaf(wsc, v1.x, acc1.x); acc1.y = fmaf(wsc, v1.y, acc1.y);
    acc2.x = fmaf(wsc, v2.x, acc2.x); acc2.y = fmaf(wsc, v2.y, acc2.y);
    acc3.x = fmaf(wsc, v3.x, acc3.x); acc3.y = fmaf(wsc, v3.y, acc3.y);
#endif
  };

#define SAMPLE_ISSUE(J)                                         \
  {                                                             \
    const int2 oo = offs[qi][J];                                \
    glds16(vb + (uint)oo.x, Gw + (((J) & 3) * 2 + 0) * 1024);   \
    glds16(vb + (uint)oo.y, Gw + (((J) & 3) * 2 + 1) * 1024);   \
  }
#define SAMPLE_CONSUME(J, N)                                              \
  {                                                                       \
    VMWAIT(N);                                                            \
    const uint4 r0 = *(const uint4*)(Gw + (((J) & 3) * 2 + 0) * 1024 + qo); \
    const uint4 r1 = *(const uint4*)(Gw + (((J) & 3) * 2 + 1) * 1024 + qo); \
    const float2 wp = wts2[qi][J][hf];                                    \
    acc16(r0, wp.x);                                                      \
    acc16(r1, wp.y);                                                      \
  }

  // half 0: taps j = 0..3 (8 loads in flight, consumed at 6/4/2/0)
  SAMPLE_ISSUE(0) SAMPLE_ISSUE(1) SAMPLE_ISSUE(2) SAMPLE_ISSUE(3)
  SAMPLE_CONSUME(0, 6) SAMPLE_CONSUME(1, 4)
  SAMPLE_CONSUME(2, 2) SAMPLE_CONSUME(3, 0)
  // half 1: taps j = 4..7
  SAMPLE_ISSUE(4) SAMPLE_ISSUE(5) SAMPLE_ISSUE(6) SAMPLE_ISSUE(7)
  SAMPLE_CONSUME(4, 6) SAMPLE_CONSUME(5, 4)
  SAMPLE_CONSUME(6, 2) SAMPLE_CONSUME(7, 0)

#undef SAMPLE_ISSUE
#undef SAMPLE_CONSUME

  // combine the two x-halves: lane ld and lane ld^4 hold the same channels
  float a[8] = {acc0.x, acc0.y, acc1.x, acc1.y,
                acc2.x, acc2.y, acc3.x, acc3.y};
#pragma unroll
  for (int k = 0; k < 8; ++k) a[k] += __shfl_xor(a[k], 4, 64);

  if (hf == 0) {
    ushort rr[8];
#pragma unroll
    for (int k = 0; k < 8; ++k) rr[k] = f2b(a[k]);
    *(uint4*)&out_pre[(size_t)m * 256 + h * 32 + ld * 8] = *(const uint4*)rr;
  }
}

extern "C" void kernel_launch(void* const* d_in, const int* in_sizes, int n_in,
                              void* d_out, int out_size, void* d_ws, size_t ws_size,
                              hipStream_t stream) {
  const float* query     = (const float*)d_in[0];
  const float* query_pos = (const float*)d_in[1];
  const float* refp      = (const float*)d_in[2];
  const float* W_so      = (const float*)d_in[3];
  const float* b_so      = (const float*)d_in[4];
  const float* W_aw      = (const float*)d_in[5];
  const float* b_aw      = (const float*)d_in[6];
  const float* W_v       = (const float*)d_in[7];
  const float* b_v       = (const float*)d_in[8];
  const float* W_o       = (const float*)d_in[9];
  const float* b_o       = (const float*)d_in[10];
  float* out = (float*)d_out;
  char* base = (char*)d_ws;

  if (ws_size >= (size_t)92618752) {
    // ---- big layout: no vt/qhi aliasing -> merged front kernel ----
    ushort* qlo     = (ushort*)base;                     // 20,480,000
    ushort* qhi     = (ushort*)(base + 20480000);        // 20,480,000
    ushort* vt      = (ushort*)(base + 40960000);        // 20,480,000
    float*  so_ws   = (float*)(base + 61440000);         // 20,480,000
    float*  aw_ws   = (float*)(base + 81920000);         // 10,240,000
    ushort* out_pre = (ushort*)base;                     // alias qlo (dead)
    ushort* WvT     = (ushort*)(base + 92160000);
    ushort* WoT     = WvT + 65536;
    ushort* WsoT    = WoT + 65536;
    ushort* WawT    = WsoT + 65536;

    prep_all<<<5896, 256, 0, stream>>>(query, query_pos, W_v, W_o, W_so, W_aw,
                                       qlo, qhi, WvT, WoT, WsoT, WawT);
    gemm_front<<<1875, 256, 0, stream>>>(qlo, qhi, WvT, WsoT, WawT,
                                         b_v, b_so, b_aw, vt, so_ws, aw_ws);
    sample_kernel<<<10000, 256, 0, stream>>>(vt, so_ws, aw_ws, refp, out_pre);
    gemm_o_k<<<dim3(625, 2), 256, 0, stream>>>(out_pre, WoT, b_o, out);
  } else {
    // ---- R4 layout (aliased, 72.1 MB) and schedule ----
    ushort* qlo     = (ushort*)base;
    ushort* qhi     = (ushort*)(base + 20480000);
    ushort* vt      = (ushort*)(base + 20480000);        // alias qhi
    ushort* out_pre = (ushort*)base;                     // alias qlo
    float*  so_ws   = (float*)(base + 40960000);
    float*  aw_ws   = (float*)(base + 61440000);
    ushort* WvT     = (ushort*)(base + 71680000);
    ushort* WoT     = WvT + 65536;
    ushort* WsoT    = WoT + 65536;
    ushort* WawT    = WsoT + 65536;

    prep_all<<<5896, 256, 0, stream>>>(query, query_pos, W_v, W_o, W_so, W_aw,
                                       qlo, qhi, WvT, WoT, WsoT, WawT);
    gemm_soaw_k<<<625, 256, 0, stream>>>(qlo, qhi, WsoT, WawT,
                                         b_so, b_aw, so_ws, aw_ws);
    gemm_v_k<<<dim3(625, 2), 256, 0, stream>>>(qlo, WvT, b_v, vt);
    sample_kernel<<<10000, 256, 0, stream>>>(vt, so_ws, aw_ws, refp, out_pre);
    gemm_o_k<<<dim3(625, 2), 256, 0, stream>>>(out_pre, WoT, b_o, out);
  }
}

// Round 9
// 226.780 us; speedup vs baseline: 1.0212x; 1.0212x over previous
//
#include <hip/hip_runtime.h>
#include <math.h>

#define NQc 40000
#define Wc 200
#define Hc 200

typedef __attribute__((ext_vector_type(8))) short short8;
typedef __attribute__((ext_vector_type(4))) float f32x4;
typedef __attribute__((ext_vector_type(2))) float f32x2;

// counted vmem wait: lets prefetch loads stay in flight across barriers
#define VMWAIT(N) asm volatile("s_waitcnt vmcnt(" #N ")" ::: "memory")

__device__ __forceinline__ ushort f2b(float f) {
  unsigned u = __float_as_uint(f);
  u = (u + 0x7fffu + ((u >> 16) & 1u)) >> 16;
  return (ushort)u;
}

// async global->LDS, 16B per lane; LDS dest is wave-uniform base + lane*16
__device__ __forceinline__ void glds16(const void* g, void* l) {
  __builtin_amdgcn_global_load_lds(
      (const __attribute__((address_space(1))) void*)g,
      (__attribute__((address_space(3))) void*)l, 16, 0, 0);
}

// ---------------------------------------------------------------------------
// prep_all: blocks [0,5000): single-pass qlo = bf16(q), qhi = bf16(q+qp) for
// the SAME 8 columns per thread (q read once). blocks [5000,5896): weights.
// ---------------------------------------------------------------------------
__global__ __launch_bounds__(256) void prep_all(
    const float* __restrict__ q, const float* __restrict__ qp,
    const float* __restrict__ Wv, const float* __restrict__ Wo,
    const float* __restrict__ Wso, const float* __restrict__ Waw,
    ushort* __restrict__ qlo, ushort* __restrict__ qhi,
    ushort* __restrict__ WvT, ushort* __restrict__ WoT,
    ushort* __restrict__ WsoT, ushort* __restrict__ WawT) {
  const int bid = blockIdx.x;
  if (bid < 5000) {
    const int flat = bid * 256 + threadIdx.x;   // 1.28M threads, 8 cols each
    const int m = flat >> 5;
    const int c8 = (flat & 31) * 8;
    const float4 a  = *(const float4*)(q  + (size_t)m * 256 + c8);
    const float4 b  = *(const float4*)(q  + (size_t)m * 256 + c8 + 4);
    const float4 ap = *(const float4*)(qp + (size_t)m * 256 + c8);
    const float4 bp = *(const float4*)(qp + (size_t)m * 256 + c8 + 4);
    ushort lo[8], hi[8];
    lo[0] = f2b(a.x); lo[1] = f2b(a.y); lo[2] = f2b(a.z); lo[3] = f2b(a.w);
    lo[4] = f2b(b.x); lo[5] = f2b(b.y); lo[6] = f2b(b.z); lo[7] = f2b(b.w);
    hi[0] = f2b(a.x + ap.x); hi[1] = f2b(a.y + ap.y);
    hi[2] = f2b(a.z + ap.z); hi[3] = f2b(a.w + ap.w);
    hi[4] = f2b(b.x + bp.x); hi[5] = f2b(b.y + bp.y);
    hi[6] = f2b(b.z + bp.z); hi[7] = f2b(b.w + bp.w);
    *(uint4*)&qlo[(size_t)m * 256 + c8] = *(const uint4*)lo;
    *(uint4*)&qhi[(size_t)m * 256 + c8] = *(const uint4*)hi;
  } else {
    const int idx = (bid - 5000) * 256 + threadIdx.x;
    if (idx < 65536) {
      int n = idx >> 8, k = idx & 255;
      WvT[idx] = f2b(Wv[k * 256 + n]);
    } else if (idx < 131072) {
      int i = idx - 65536;
      int n = i >> 8, k = i & 255;
      WoT[i] = f2b(Wo[k * 256 + n]);
    } else if (idx < 196608) {
      int i = idx - 131072;
      int n = i >> 9, k = i & 511;
      WsoT[i] = f2b(Wso[k * 128 + n]);
    } else {
      int i = idx - 196608;
      int n = i >> 9, k = i & 511;
      WawT[i] = f2b(Waw[k * 64 + n]);
    }
  }
}

// ---------------------------------------------------------------------------
// Swizzle convention for unpadded LDS tiles (64 ushorts = 8 chunks of 16B/row):
// LDS slot (row, c) holds global 16B-chunk (c ^ (row & 7)). glds writes are
// lane-contiguous (base + lane*16); ds_read_b128 spreads banks 2-way max.
//
// K-loops: counted-vmcnt 2-deep pipeline (catalog T3+T4). Per step:
//   STAGE(t+1) -> s_waitcnt vmcnt(L) -> s_barrier -> MFMA(buf cur) -> s_barrier
// vmcnt never drains to 0 inside the loop; only glds16 touches vmem in-loop.
// ---------------------------------------------------------------------------

// [so|aw] = [qlo | qhi] @ [WsoT(128)|WawT(64)]^T, N=192, K=512, BM=64.
__global__ __launch_bounds__(256, 2) void gemm_soaw_k(
    const ushort* __restrict__ qlo, const ushort* __restrict__ qhi,
    const ushort* __restrict__ WsoT, const ushort* __restrict__ WawT,
    const float* __restrict__ b_so, const float* __restrict__ b_aw,
    float* __restrict__ so_ws, float* __restrict__ aw_ws) {
  __shared__ __align__(16) char smem[65536];
  float (*E)[68] = (float(*)[68])smem;
  f32x4 acc[12] = {};
  const int m0 = blockIdx.x * 64;
  const int tid = threadIdx.x;
  const int w = tid >> 6, lane = tid & 63;
  const int rl = lane & 15, q2 = lane >> 4;
  const int sw8 = rl & 7;
  const int lrow = lane >> 3, lch = (lane & 7) ^ (lrow & 7);

  auto STAGE = [&](int buf, int t) {
    ushort* As = (ushort*)(smem + buf * 32768);
    ushort* Bs = As + 4096;
    const int k0 = t * 64;
    const ushort* aq = (k0 < 256) ? qlo : qhi;
    const int ka = k0 & 255;
#pragma unroll
    for (int i = 0; i < 2; ++i) {
      const int g = w * 2 + i;
      const int row = g * 8 + lrow;
      glds16(aq + (size_t)(m0 + row) * 256 + ka + lch * 8,
             As + g * 512 + lane * 8);
    }
#pragma unroll
    for (int i = 0; i < 6; ++i) {
      const int g = w * 6 + i;
      const int row = g * 8 + lrow;
      const ushort* gsrc = (row < 128)
          ? WsoT + (size_t)row * 512 + k0 + lch * 8
          : WawT + (size_t)(row - 128) * 512 + k0 + lch * 8;
      glds16(gsrc, Bs + g * 512 + lane * 8);
    }
  };

  STAGE(0, 0);
#pragma unroll
  for (int t = 0; t < 8; ++t) {
    const int cur = t & 1;
    if (t < 7) { STAGE(cur ^ 1, t + 1); VMWAIT(8); }
    else       { VMWAIT(0); }
    __builtin_amdgcn_s_barrier();
    {
      const ushort* Asb = (const ushort*)(smem + cur * 32768);
      const ushort* Bsb = Asb + 4096;
#pragma unroll
      for (int kk = 0; kk < 2; ++kk) {
        const short8 af = *(const short8*)
            &Asb[(w * 16 + rl) * 64 + ((kk * 4 + q2) ^ sw8) * 8];
#pragma unroll
        for (int nj = 0; nj < 12; ++nj) {
          const short8 bf = *(const short8*)
              &Bsb[(nj * 16 + rl) * 64 + ((kk * 4 + q2) ^ sw8) * 8];
          acc[nj] = __builtin_amdgcn_mfma_f32_16x16x32_bf16(af, bf, acc[nj], 0, 0, 0);
        }
      }
    }
    __builtin_amdgcn_s_barrier();
  }

  const int rbase = q2 * 4, cl = rl;
#pragma unroll
  for (int p = 0; p < 3; ++p) {
#pragma unroll
    for (int j = 0; j < 4; ++j) {
      const int nj = p * 4 + j;
      const int nl = j * 16 + cl;
      const f32x4 a = acc[nj];
      if (p < 2) {
        const float bb = b_so[p * 64 + nl];
#pragma unroll
        for (int r = 0; r < 4; ++r)
          E[w * 16 + rbase + r][nl] = a[r] + bb;
      } else {
        const float bb = b_aw[nl];
#pragma unroll
        for (int r = 0; r < 4; ++r) {
          float z = a[r] + bb;
          float zm = fmaxf(z, __shfl_xor(z, 1, 64));
          zm = fmaxf(zm, __shfl_xor(zm, 2, 64));
          float e = expf(z - zm);
          float s = e + __shfl_xor(e, 1, 64);
          s = s + __shfl_xor(s, 2, 64);
          E[w * 16 + rbase + r][nl] = e / s;
        }
      }
    }
    __syncthreads();
#pragma unroll
    for (int it = 0; it < 4; ++it) {
      const int flat = it * 256 + tid;
      const int row = flat >> 4, c4 = (flat & 15) * 4;
      const float4 vle = *(const float4*)&E[row][c4];
      if (p < 2)
        *(float4*)&so_ws[(size_t)(m0 + row) * 128 + p * 64 + c4] = vle;
      else
        *(float4*)&aw_ws[(size_t)(m0 + row) * 64 + c4] = vle;
    }
    __syncthreads();
  }
}

// v = qlo @ WvT + b_v -> bf16 head-major vt (NH, NQ, 32). N=128/block, K=256.
__global__ __launch_bounds__(256, 3) void gemm_v_k(
    const ushort* __restrict__ qlo, const ushort* __restrict__ WvT,
    const float* __restrict__ bv, ushort* __restrict__ vt) {
  __shared__ __align__(16) char smem[49152];
  ushort (*Eb)[72] = (ushort(*)[72])smem;
  f32x4 acc[8] = {};
  const int m0 = blockIdx.x * 64, n0 = blockIdx.y * 128;
  const int tid = threadIdx.x;
  const int w = tid >> 6, lane = tid & 63;
  const int rl = lane & 15, q2 = lane >> 4;
  const int sw8 = rl & 7;
  const int lrow = lane >> 3, lch = (lane & 7) ^ (lrow & 7);

  auto STAGE = [&](int buf, int t) {
    ushort* As = (ushort*)(smem + buf * 24576);
    ushort* Bs = As + 4096;
    const int k0 = t * 64;
#pragma unroll
    for (int i = 0; i < 2; ++i) {
      const int g = w * 2 + i;
      const int row = g * 8 + lrow;
      glds16(qlo + (size_t)(m0 + row) * 256 + k0 + lch * 8,
             As + g * 512 + lane * 8);
    }
#pragma unroll
    for (int i = 0; i < 4; ++i) {
      const int g = w * 4 + i;
      const int row = g * 8 + lrow;
      glds16(WvT + (size_t)(n0 + row) * 256 + k0 + lch * 8,
             Bs + g * 512 + lane * 8);
    }
  };

  STAGE(0, 0);
#pragma unroll
  for (int t = 0; t < 4; ++t) {
    const int cur = t & 1;
    if (t < 3) { STAGE(cur ^ 1, t + 1); VMWAIT(6); }
    else       { VMWAIT(0); }
    __builtin_amdgcn_s_barrier();
    {
      const ushort* Asb = (const ushort*)(smem + cur * 24576);
      const ushort* Bsb = Asb + 4096;
#pragma unroll
      for (int kk = 0; kk < 2; ++kk) {
        const short8 af = *(const short8*)
            &Asb[(w * 16 + rl) * 64 + ((kk * 4 + q2) ^ sw8) * 8];
#pragma unroll
        for (int nj = 0; nj < 8; ++nj) {
          const short8 bf = *(const short8*)
              &Bsb[(nj * 16 + rl) * 64 + ((kk * 4 + q2) ^ sw8) * 8];
          acc[nj] = __builtin_amdgcn_mfma_f32_16x16x32_bf16(af, bf, acc[nj], 0, 0, 0);
        }
      }
    }
    __builtin_amdgcn_s_barrier();
  }

  const int rbase = q2 * 4, cl = rl;
#pragma unroll
  for (int p = 0; p < 2; ++p) {
#pragma unroll
    for (int j = 0; j < 4; ++j) {
      const int nj = p * 4 + j;
      const int n = n0 + p * 64 + j * 16 + cl;
      const float bb = bv[n];
      const f32x4 a = acc[nj];
#pragma unroll
      for (int r = 0; r < 4; ++r)
        Eb[w * 16 + rbase + r][j * 16 + cl] = f2b(a[r] + bb);
    }
    __syncthreads();
#pragma unroll
    for (int hh = 0; hh < 2; ++hh) {
      const int h = (n0 + p * 64) / 32 + hh;
#pragma unroll
      for (int it = 0; it < 2; ++it) {
        const int flat = it * 256 + tid;
        const int row = flat >> 3, d4 = (flat & 7) * 4;
        *(ushort4*)&vt[((size_t)h * NQc + m0 + row) * 32 + d4] =
            *(const ushort4*)&Eb[row][hh * 32 + d4];
      }
    }
    __syncthreads();
  }
}

// ---------------------------------------------------------------------------
// gemm_front: soaw + v merged into ONE launch (used only when workspace
// permits non-aliased vt). bid<1250: v path; bid>=1250: soaw path.
// ---------------------------------------------------------------------------
__global__ __launch_bounds__(256, 2) void gemm_front(
    const ushort* __restrict__ qlo, const ushort* __restrict__ qhi,
    const ushort* __restrict__ WvT, const ushort* __restrict__ WsoT,
    const ushort* __restrict__ WawT,
    const float* __restrict__ bv, const float* __restrict__ b_so,
    const float* __restrict__ b_aw,
    ushort* __restrict__ vt, float* __restrict__ so_ws,
    float* __restrict__ aw_ws) {
  __shared__ __align__(16) char smem[65536];
  const int tid = threadIdx.x;
  const int w = tid >> 6, lane = tid & 63;
  const int rl = lane & 15, q2 = lane >> 4;
  const int sw8 = rl & 7;
  const int lrow = lane >> 3, lch = (lane & 7) ^ (lrow & 7);
  const int bid = blockIdx.x;

  if (bid < 1250) {
    // ================= v path =================
    ushort (*Eb)[72] = (ushort(*)[72])smem;
    f32x4 acc[8] = {};
    const int m0 = (bid >> 1) * 64, n0 = (bid & 1) * 128;

    auto STAGE = [&](int buf, int t) {
      ushort* As = (ushort*)(smem + buf * 24576);
      ushort* Bs = As + 4096;
      const int k0 = t * 64;
#pragma unroll
      for (int i = 0; i < 2; ++i) {
        const int g = w * 2 + i;
        const int row = g * 8 + lrow;
        glds16(qlo + (size_t)(m0 + row) * 256 + k0 + lch * 8,
               As + g * 512 + lane * 8);
      }
#pragma unroll
      for (int i = 0; i < 4; ++i) {
        const int g = w * 4 + i;
        const int row = g * 8 + lrow;
        glds16(WvT + (size_t)(n0 + row) * 256 + k0 + lch * 8,
               Bs + g * 512 + lane * 8);
      }
    };

    STAGE(0, 0);
#pragma unroll
    for (int t = 0; t < 4; ++t) {
      const int cur = t & 1;
      if (t < 3) { STAGE(cur ^ 1, t + 1); VMWAIT(6); }
      else       { VMWAIT(0); }
      __builtin_amdgcn_s_barrier();
      {
        const ushort* Asb = (const ushort*)(smem + cur * 24576);
        const ushort* Bsb = Asb + 4096;
#pragma unroll
        for (int kk = 0; kk < 2; ++kk) {
          const short8 af = *(const short8*)
              &Asb[(w * 16 + rl) * 64 + ((kk * 4 + q2) ^ sw8) * 8];
#pragma unroll
          for (int nj = 0; nj < 8; ++nj) {
            const short8 bf = *(const short8*)
                &Bsb[(nj * 16 + rl) * 64 + ((kk * 4 + q2) ^ sw8) * 8];
            acc[nj] = __builtin_amdgcn_mfma_f32_16x16x32_bf16(af, bf, acc[nj], 0, 0, 0);
          }
        }
      }
      __builtin_amdgcn_s_barrier();
    }

    const int rbase = q2 * 4, cl = rl;
#pragma unroll
    for (int p = 0; p < 2; ++p) {
#pragma unroll
      for (int j = 0; j < 4; ++j) {
        const int nj = p * 4 + j;
        const int n = n0 + p * 64 + j * 16 + cl;
        const float bb = bv[n];
        const f32x4 a = acc[nj];
#pragma unroll
        for (int r = 0; r < 4; ++r)
          Eb[w * 16 + rbase + r][j * 16 + cl] = f2b(a[r] + bb);
      }
      __syncthreads();
#pragma unroll
      for (int hh = 0; hh < 2; ++hh) {
        const int h = (n0 + p * 64) / 32 + hh;
#pragma unroll
        for (int it = 0; it < 2; ++it) {
          const int flat = it * 256 + tid;
          const int row = flat >> 3, d4 = (flat & 7) * 4;
          *(ushort4*)&vt[((size_t)h * NQc + m0 + row) * 32 + d4] =
              *(const ushort4*)&Eb[row][hh * 32 + d4];
        }
      }
      __syncthreads();
    }
  } else {
    // ================= soaw path =================
    float (*E)[68] = (float(*)[68])smem;
    f32x4 acc[12] = {};
    const int m0 = (bid - 1250) * 64;

    auto STAGE = [&](int buf, int t) {
      ushort* As = (ushort*)(smem + buf * 32768);
      ushort* Bs = As + 4096;
      const int k0 = t * 64;
      const ushort* aq = (k0 < 256) ? qlo : qhi;
      const int ka = k0 & 255;
#pragma unroll
      for (int i = 0; i < 2; ++i) {
        const int g = w * 2 + i;
        const int row = g * 8 + lrow;
        glds16(aq + (size_t)(m0 + row) * 256 + ka + lch * 8,
               As + g * 512 + lane * 8);
      }
#pragma unroll
      for (int i = 0; i < 6; ++i) {
        const int g = w * 6 + i;
        const int row = g * 8 + lrow;
        const ushort* gsrc = (row < 128)
            ? WsoT + (size_t)row * 512 + k0 + lch * 8
            : WawT + (size_t)(row - 128) * 512 + k0 + lch * 8;
        glds16(gsrc, Bs + g * 512 + lane * 8);
      }
    };

    STAGE(0, 0);
#pragma unroll
    for (int t = 0; t < 8; ++t) {
      const int cur = t & 1;
      if (t < 7) { STAGE(cur ^ 1, t + 1); VMWAIT(8); }
      else       { VMWAIT(0); }
      __builtin_amdgcn_s_barrier();
      {
        const ushort* Asb = (const ushort*)(smem + cur * 32768);
        const ushort* Bsb = Asb + 4096;
#pragma unroll
        for (int kk = 0; kk < 2; ++kk) {
          const short8 af = *(const short8*)
              &Asb[(w * 16 + rl) * 64 + ((kk * 4 + q2) ^ sw8) * 8];
#pragma unroll
          for (int nj = 0; nj < 12; ++nj) {
            const short8 bf = *(const short8*)
                &Bsb[(nj * 16 + rl) * 64 + ((kk * 4 + q2) ^ sw8) * 8];
            acc[nj] = __builtin_amdgcn_mfma_f32_16x16x32_bf16(af, bf, acc[nj], 0, 0, 0);
          }
        }
      }
      __builtin_amdgcn_s_barrier();
    }

    const int rbase = q2 * 4, cl = rl;
#pragma unroll
    for (int p = 0; p < 3; ++p) {
#pragma unroll
      for (int j = 0; j < 4; ++j) {
        const int nj = p * 4 + j;
        const int nl = j * 16 + cl;
        const f32x4 a = acc[nj];
        if (p < 2) {
          const float bb = b_so[p * 64 + nl];
#pragma unroll
          for (int r = 0; r < 4; ++r)
            E[w * 16 + rbase + r][nl] = a[r] + bb;
        } else {
          const float bb = b_aw[nl];
#pragma unroll
          for (int r = 0; r < 4; ++r) {
            float z = a[r] + bb;
            float zm = fmaxf(z, __shfl_xor(z, 1, 64));
            zm = fmaxf(zm, __shfl_xor(zm, 2, 64));
            float e = expf(z - zm);
            float s = e + __shfl_xor(e, 1, 64);
            s = s + __shfl_xor(s, 2, 64);
            E[w * 16 + rbase + r][nl] = e / s;
          }
        }
      }
      __syncthreads();
#pragma unroll
      for (int it = 0; it < 4; ++it) {
        const int flat = it * 256 + tid;
        const int row = flat >> 4, c4 = (flat & 15) * 4;
        const float4 vle = *(const float4*)&E[row][c4];
        if (p < 2)
          *(float4*)&so_ws[(size_t)(m0 + row) * 128 + p * 64 + c4] = vle;
        else
          *(float4*)&aw_ws[(size_t)(m0 + row) * 64 + c4] = vle;
      }
      __syncthreads();
    }
  }
}

// out = out_pre @ WoT + b_o -> fp32. N=128/block, K=256. Counted-vmcnt dbuf.
__global__ __launch_bounds__(256, 3) void gemm_o_k(
    const ushort* __restrict__ Ap, const ushort* __restrict__ WoT,
    const float* __restrict__ bo, float* __restrict__ out) {
  __shared__ __align__(16) char smem[49152];
  float (*E)[68] = (float(*)[68])smem;
  f32x4 acc[8] = {};
  const int m0 = blockIdx.x * 64, n0 = blockIdx.y * 128;
  const int tid = threadIdx.x;
  const int w = tid >> 6, lane = tid & 63;
  const int rl = lane & 15, q2 = lane >> 4;
  const int sw8 = rl & 7;
  const int lrow = lane >> 3, lch = (lane & 7) ^ (lrow & 7);

  auto STAGE = [&](int buf, int t) {
    ushort* As = (ushort*)(smem + buf * 24576);
    ushort* Bs = As + 4096;
    const int k0 = t * 64;
#pragma unroll
    for (int i = 0; i < 2; ++i) {
      const int g = w * 2 + i;
      const int row = g * 8 + lrow;
      glds16(Ap + (size_t)(m0 + row) * 256 + k0 + lch * 8,
             As + g * 512 + lane * 8);
    }
#pragma unroll
    for (int i = 0; i < 4; ++i) {
      const int g = w * 4 + i;
      const int row = g * 8 + lrow;
      glds16(WoT + (size_t)(n0 + row) * 256 + k0 + lch * 8,
             Bs + g * 512 + lane * 8);
    }
  };

  STAGE(0, 0);
#pragma unroll
  for (int t = 0; t < 4; ++t) {
    const int cur = t & 1;
    if (t < 3) { STAGE(cur ^ 1, t + 1); VMWAIT(6); }
    else       { VMWAIT(0); }
    __builtin_amdgcn_s_barrier();
    {
      const ushort* Asb = (const ushort*)(smem + cur * 24576);
      const ushort* Bsb = Asb + 4096;
#pragma unroll
      for (int kk = 0; kk < 2; ++kk) {
        const short8 af = *(const short8*)
            &Asb[(w * 16 + rl) * 64 + ((kk * 4 + q2) ^ sw8) * 8];
#pragma unroll
        for (int nj = 0; nj < 8; ++nj) {
          const short8 bf = *(const short8*)
              &Bsb[(nj * 16 + rl) * 64 + ((kk * 4 + q2) ^ sw8) * 8];
          acc[nj] = __builtin_amdgcn_mfma_f32_16x16x32_bf16(af, bf, acc[nj], 0, 0, 0);
        }
      }
    }
    __builtin_amdgcn_s_barrier();
  }

  const int rbase = q2 * 4, cl = rl;
#pragma unroll
  for (int p = 0; p < 2; ++p) {
#pragma unroll
    for (int j = 0; j < 4; ++j) {
      const int nj = p * 4 + j;
      const int n = n0 + p * 64 + j * 16 + cl;
      const float bb = bo[n];
      const f32x4 a = acc[nj];
#pragma unroll
      for (int r = 0; r < 4; ++r)
        E[w * 16 + rbase + r][j * 16 + cl] = a[r] + bb;
    }
    __syncthreads();
#pragma unroll
    for (int it = 0; it < 4; ++it) {
      const int flat = it * 256 + tid;
      const int row = flat >> 4, c4 = (flat & 15) * 4;
      *(float4*)&out[(size_t)(m0 + row) * 256 + n0 + p * 64 + c4] =
          *(const float4*)&E[row][c4];
    }
    __syncthreads();
  }
}

// ---------------------------------------------------------------------------
// Deformable sampling v6: block = one head x 32 queries; head = blockIdx.x & 7
// pins each head's 2.56 MB vt slice to one XCD's L2.
//
// Phase 2 gather: 16 inline-asm global_load_dwordx4 with "=v" outputs —
// issue order preserved, destinations pinned in VGPRs, the compiler CANNOT
// re-serialize (R2/R7 showed it sinks plain loads to ~6 deep; R8 showed
// glds16 gather is worse). Consumed pair-by-pair under counted
// s_waitcnt vmcnt(14..0) + sched_barrier(0) (rule #18 fence). Math unchanged.
// ---------------------------------------------------------------------------
__global__ __launch_bounds__(256) void sample_kernel(
    const ushort* __restrict__ vt,    // (NH, NQ, 32) bf16
    const float* __restrict__ so_ws,  // (NQ, 128)
    const float* __restrict__ aw_ws,  // (NQ, 64)
    const float* __restrict__ refp,   // (NQ, 2)
    ushort* __restrict__ out_pre)     // (NQ, 256) bf16
{
  __shared__ int2   offs[32][9];
  __shared__ float2 wts2[32][9][2];
  const int h  = blockIdx.x & 7;
  const int m0 = (blockIdx.x >> 3) * 32;
  const int tid = threadIdx.x;

  {
    const int j  = tid & 7;
    const int qi = tid >> 3;
    const int m  = m0 + qi;
    const int c  = h * 8 + j;
    const float sx  = so_ws[(size_t)m * 128 + c * 2 + 0];
    const float sy  = so_ws[(size_t)m * 128 + c * 2 + 1];
    const float wgt = 0.5f * aw_ws[(size_t)m * 64 + c];
    const float x = refp[m * 2 + 0] * (float)Wc + sx - 0.5f;
    const float y = refp[m * 2 + 1] * (float)Hc + sy - 0.5f;
    const float x0f = floorf(x), y0f = floorf(y);
    const int x0 = (int)x0f, y0 = (int)y0f;
    const int x1 = x0 + 1, y1 = y0 + 1;
    const float wx1 = x - x0f, wx0 = 1.0f - wx1;
    const float wy1 = y - y0f, wy0 = 1.0f - wy1;
    const float wx0v = (x0 >= 0 && x0 < Wc) ? wx0 : 0.0f;
    const float wx1v = (x1 >= 0 && x1 < Wc) ? wx1 : 0.0f;
    const float wy0v = ((y0 >= 0 && y0 < Hc) ? wy0 : 0.0f) * wgt;
    const float wy1v = ((y1 >= 0 && y1 < Hc) ? wy1 : 0.0f) * wgt;
    const int bx = min(max(x0, 0), Wc - 2);
    const float wl = (bx == x0) ? wx0v : ((bx == x1) ? wx1v : 0.0f);
    const float wr = (bx + 1 == x1) ? wx1v : ((bx + 1 == x0) ? wx0v : 0.0f);
    const int cy0 = min(max(y0, 0), Hc - 1);
    const int cy1 = min(max(y1, 0), Hc - 1);
    offs[qi][j] = make_int2((cy0 * Wc + bx) * 64, (cy1 * Wc + bx) * 64);
    wts2[qi][j][0] = make_float2(wl * wy0v, wl * wy1v);
    wts2[qi][j][1] = make_float2(wr * wy0v, wr * wy1v);
  }
  __syncthreads();

  const int qi = tid >> 3;
  const int ld = tid & 7;
  const int m  = m0 + qi;
  const int hf = ld >> 2;
  const char* __restrict__ vb =
      (const char*)(vt + (size_t)h * NQc * 32) + (uint)(ld * 16);

  f32x2 acc0 = {0.0f, 0.0f}, acc1 = {0.0f, 0.0f};
  f32x2 acc2 = {0.0f, 0.0f}, acc3 = {0.0f, 0.0f};

  auto acc16 = [&](uint4 rawv, float wsc) {
    const f32x2 wv = {wsc, wsc};
    f32x2 v0, v1, v2, v3;
    v0.x = __uint_as_float(rawv.x << 16);
    v0.y = __uint_as_float(rawv.x & 0xFFFF0000u);
    v1.x = __uint_as_float(rawv.y << 16);
    v1.y = __uint_as_float(rawv.y & 0xFFFF0000u);
    v2.x = __uint_as_float(rawv.z << 16);
    v2.y = __uint_as_float(rawv.z & 0xFFFF0000u);
    v3.x = __uint_as_float(rawv.w << 16);
    v3.y = __uint_as_float(rawv.w & 0xFFFF0000u);
#if __has_builtin(__builtin_elementwise_fma)
    acc0 = __builtin_elementwise_fma(wv, v0, acc0);
    acc1 = __builtin_elementwise_fma(wv, v1, acc1);
    acc2 = __builtin_elementwise_fma(wv, v2, acc2);
    acc3 = __builtin_elementwise_fma(wv, v3, acc3);
#else
    acc0.x = fmaf(wsc, v0.x, acc0.x); acc0.y = fmaf(wsc, v0.y, acc0.y);
    acc1.x = fmaf(wsc, v1.x, acc1.x); acc1.y = fmaf(wsc, v1.y, acc1.y);
    acc2.x = fmaf(wsc, v2.x, acc2.x); acc2.y = fmaf(wsc, v2.y, acc2.y);
    acc3.x = fmaf(wsc, v3.x, acc3.x); acc3.y = fmaf(wsc, v3.y, acc3.y);
#endif
  };

  // issue all 16 loads via inline asm (pinned VGPR dests, fixed order)
  uint4 R0, R1, R2, R3, R4, R5, R6, R7, R8, R9, R10, R11, R12, R13, R14, R15;
#define GLD(dst, boff)                                               \
  asm volatile("global_load_dwordx4 %0, %1, off"                     \
               : "=v"(dst)                                           \
               : "v"((unsigned long long)(vb + (uint)(boff)))        \
               : "memory")
  {
    int2 o;
    o = offs[qi][0]; GLD(R0,  o.x); GLD(R1,  o.y);
    o = offs[qi][1]; GLD(R2,  o.x); GLD(R3,  o.y);
    o = offs[qi][2]; GLD(R4,  o.x); GLD(R5,  o.y);
    o = offs[qi][3]; GLD(R6,  o.x); GLD(R7,  o.y);
    o = offs[qi][4]; GLD(R8,  o.x); GLD(R9,  o.y);
    o = offs[qi][5]; GLD(R10, o.x); GLD(R11, o.y);
    o = offs[qi][6]; GLD(R12, o.x); GLD(R13, o.y);
    o = offs[qi][7]; GLD(R14, o.x); GLD(R15, o.y);
  }
#undef GLD

#define CONSUME(J, RA, RB, N)                  \
  {                                            \
    VMWAIT(N);                                 \
    __builtin_amdgcn_sched_barrier(0);         \
    const float2 wp = wts2[qi][J][hf];         \
    acc16(RA, wp.x);                           \
    acc16(RB, wp.y);                           \
  }
  CONSUME(0, R0,  R1,  14)
  CONSUME(1, R2,  R3,  12)
  CONSUME(2, R4,  R5,  10)
  CONSUME(3, R6,  R7,  8)
  CONSUME(4, R8,  R9,  6)
  CONSUME(5, R10, R11, 4)
  CONSUME(6, R12, R13, 2)
  CONSUME(7, R14, R15, 0)
#undef CONSUME

  // combine the two x-halves: lane ld and lane ld^4 hold the same channels
  float a[8] = {acc0.x, acc0.y, acc1.x, acc1.y,
                acc2.x, acc2.y, acc3.x, acc3.y};
#pragma unroll
  for (int k = 0; k < 8; ++k) a[k] += __shfl_xor(a[k], 4, 64);

  if (hf == 0) {
    ushort rr[8];
#pragma unroll
    for (int k = 0; k < 8; ++k) rr[k] = f2b(a[k]);
    *(uint4*)&out_pre[(size_t)m * 256 + h * 32 + ld * 8] = *(const uint4*)rr;
  }
}

extern "C" void kernel_launch(void* const* d_in, const int* in_sizes, int n_in,
                              void* d_out, int out_size, void* d_ws, size_t ws_size,
                              hipStream_t stream) {
  const float* query     = (const float*)d_in[0];
  const float* query_pos = (const float*)d_in[1];
  const float* refp      = (const float*)d_in[2];
  const float* W_so      = (const float*)d_in[3];
  const float* b_so      = (const float*)d_in[4];
  const float* W_aw      = (const float*)d_in[5];
  const float* b_aw      = (const float*)d_in[6];
  const float* W_v       = (const float*)d_in[7];
  const float* b_v       = (const float*)d_in[8];
  const float* W_o       = (const float*)d_in[9];
  const float* b_o       = (const float*)d_in[10];
  float* out = (float*)d_out;
  char* base = (char*)d_ws;

  if (ws_size >= (size_t)92618752) {
    // ---- big layout: no vt/qhi aliasing -> merged front kernel ----
    ushort* qlo     = (ushort*)base;                     // 20,480,000
    ushort* qhi     = (ushort*)(base + 20480000);        // 20,480,000
    ushort* vt      = (ushort*)(base + 40960000);        // 20,480,000
    float*  so_ws   = (float*)(base + 61440000);         // 20,480,000
    float*  aw_ws   = (float*)(base + 81920000);         // 10,240,000
    ushort* out_pre = (ushort*)base;                     // alias qlo (dead)
    ushort* WvT     = (ushort*)(base + 92160000);
    ushort* WoT     = WvT + 65536;
    ushort* WsoT    = WoT + 65536;
    ushort* WawT    = WsoT + 65536;

    prep_all<<<5896, 256, 0, stream>>>(query, query_pos, W_v, W_o, W_so, W_aw,
                                       qlo, qhi, WvT, WoT, WsoT, WawT);
    gemm_front<<<1875, 256, 0, stream>>>(qlo, qhi, WvT, WsoT, WawT,
                                         b_v, b_so, b_aw, vt, so_ws, aw_ws);
    sample_kernel<<<10000, 256, 0, stream>>>(vt, so_ws, aw_ws, refp, out_pre);
    gemm_o_k<<<dim3(625, 2), 256, 0, stream>>>(out_pre, WoT, b_o, out);
  } else {
    // ---- R4 layout (aliased, 72.1 MB) and schedule ----
    ushort* qlo     = (ushort*)base;
    ushort* qhi     = (ushort*)(base + 20480000);
    ushort* vt      = (ushort*)(base + 20480000);        // alias qhi
    ushort* out_pre = (ushort*)base;                     // alias qlo
    float*  so_ws   = (float*)(base + 40960000);
    float*  aw_ws   = (float*)(base + 61440000);
    ushort* WvT     = (ushort*)(base + 71680000);
    ushort* WoT     = WvT + 65536;
    ushort* WsoT    = WoT + 65536;
    ushort* WawT    = WsoT + 65536;

    prep_all<<<5896, 256, 0, stream>>>(query, query_pos, W_v, W_o, W_so, W_aw,
                                       qlo, qhi, WvT, WoT, WsoT, WawT);
    gemm_soaw_k<<<625, 256, 0, stream>>>(qlo, qhi, WsoT, WawT,
                                         b_so, b_aw, so_ws, aw_ws);
    gemm_v_k<<<dim3(625, 2), 256, 0, stream>>>(qlo, WvT, b_v, vt);
    sample_kernel<<<10000, 256, 0, stream>>>(vt, so_ws, aw_ws, refp, out_pre);
    gemm_o_k<<<dim3(625, 2), 256, 0, stream>>>(out_pre, WoT, b_o, out);
  }
}

// Round 11
// 224.719 us; speedup vs baseline: 1.0306x; 1.0092x over previous
//
#include <hip/hip_runtime.h>
#include <math.h>

#define NQc 40000
#define Wc 200
#define Hc 200

typedef __attribute__((ext_vector_type(8))) short short8;
typedef __attribute__((ext_vector_type(4))) float f32x4;
typedef __attribute__((ext_vector_type(2))) float f32x2;

// counted vmem wait: lets prefetch loads stay in flight across barriers
#define VMWAIT(N) asm volatile("s_waitcnt vmcnt(" #N ")" ::: "memory")

__device__ __forceinline__ ushort f2b(float f) {
  unsigned u = __float_as_uint(f);
  u = (u + 0x7fffu + ((u >> 16) & 1u)) >> 16;
  return (ushort)u;
}

// async global->LDS, 16B per lane; LDS dest must be base + lane*16 contiguous
__device__ __forceinline__ void glds16(const void* g, void* l) {
  __builtin_amdgcn_global_load_lds(
      (const __attribute__((address_space(1))) void*)g,
      (__attribute__((address_space(3))) void*)l, 16, 0, 0);
}

// ---------------------------------------------------------------------------
// prep_all: blocks [0,5000): single-pass qlo = bf16(q), qhi = bf16(q+qp) for
// the SAME 8 columns per thread (q read once). blocks [5000,5896): weights.
// ---------------------------------------------------------------------------
__global__ __launch_bounds__(256) void prep_all(
    const float* __restrict__ q, const float* __restrict__ qp,
    const float* __restrict__ Wv, const float* __restrict__ Wo,
    const float* __restrict__ Wso, const float* __restrict__ Waw,
    ushort* __restrict__ qlo, ushort* __restrict__ qhi,
    ushort* __restrict__ WvT, ushort* __restrict__ WoT,
    ushort* __restrict__ WsoT, ushort* __restrict__ WawT) {
  const int bid = blockIdx.x;
  if (bid < 5000) {
    const int flat = bid * 256 + threadIdx.x;   // 1.28M threads, 8 cols each
    const int m = flat >> 5;
    const int c8 = (flat & 31) * 8;
    const float4 a  = *(const float4*)(q  + (size_t)m * 256 + c8);
    const float4 b  = *(const float4*)(q  + (size_t)m * 256 + c8 + 4);
    const float4 ap = *(const float4*)(qp + (size_t)m * 256 + c8);
    const float4 bp = *(const float4*)(qp + (size_t)m * 256 + c8 + 4);
    ushort lo[8], hi[8];
    lo[0] = f2b(a.x); lo[1] = f2b(a.y); lo[2] = f2b(a.z); lo[3] = f2b(a.w);
    lo[4] = f2b(b.x); lo[5] = f2b(b.y); lo[6] = f2b(b.z); lo[7] = f2b(b.w);
    hi[0] = f2b(a.x + ap.x); hi[1] = f2b(a.y + ap.y);
    hi[2] = f2b(a.z + ap.z); hi[3] = f2b(a.w + ap.w);
    hi[4] = f2b(b.x + bp.x); hi[5] = f2b(b.y + bp.y);
    hi[6] = f2b(b.z + bp.z); hi[7] = f2b(b.w + bp.w);
    *(uint4*)&qlo[(size_t)m * 256 + c8] = *(const uint4*)lo;
    *(uint4*)&qhi[(size_t)m * 256 + c8] = *(const uint4*)hi;
  } else {
    const int idx = (bid - 5000) * 256 + threadIdx.x;
    if (idx < 65536) {
      int n = idx >> 8, k = idx & 255;
      WvT[idx] = f2b(Wv[k * 256 + n]);
    } else if (idx < 131072) {
      int i = idx - 65536;
      int n = i >> 8, k = i & 255;
      WoT[i] = f2b(Wo[k * 256 + n]);
    } else if (idx < 196608) {
      int i = idx - 131072;
      int n = i >> 9, k = i & 511;
      WsoT[i] = f2b(Wso[k * 128 + n]);
    } else {
      int i = idx - 196608;
      int n = i >> 9, k = i & 511;
      WawT[i] = f2b(Waw[k * 64 + n]);
    }
  }
}

// ---------------------------------------------------------------------------
// Swizzle convention for unpadded LDS tiles (64 ushorts = 8 chunks of 16B/row):
// LDS slot (row, c) holds global 16B-chunk (c ^ (row & 7)). glds writes are
// lane-contiguous (base + lane*16); ds_read_b128 spreads banks 2-way max.
//
// K-loops: counted-vmcnt 2-deep pipeline (catalog T3+T4). Per step:
//   STAGE(t+1) -> s_waitcnt vmcnt(L) -> s_barrier -> MFMA(buf cur) -> s_barrier
// vmcnt never drains to 0 inside the loop; only glds16 touches vmem in-loop.
// ---------------------------------------------------------------------------

// [so|aw] = [qlo | qhi] @ [WsoT(128)|WawT(64)]^T, N=192, K=512, BM=64.
__global__ __launch_bounds__(256, 2) void gemm_soaw_k(
    const ushort* __restrict__ qlo, const ushort* __restrict__ qhi,
    const ushort* __restrict__ WsoT, const ushort* __restrict__ WawT,
    const float* __restrict__ b_so, const float* __restrict__ b_aw,
    float* __restrict__ so_ws, float* __restrict__ aw_ws) {
  __shared__ __align__(16) char smem[65536];
  float (*E)[68] = (float(*)[68])smem;
  f32x4 acc[12] = {};
  const int m0 = blockIdx.x * 64;
  const int tid = threadIdx.x;
  const int w = tid >> 6, lane = tid & 63;
  const int rl = lane & 15, q2 = lane >> 4;
  const int sw8 = rl & 7;
  const int lrow = lane >> 3, lch = (lane & 7) ^ (lrow & 7);

  auto STAGE = [&](int buf, int t) {
    ushort* As = (ushort*)(smem + buf * 32768);
    ushort* Bs = As + 4096;
    const int k0 = t * 64;
    const ushort* aq = (k0 < 256) ? qlo : qhi;
    const int ka = k0 & 255;
#pragma unroll
    for (int i = 0; i < 2; ++i) {
      const int g = w * 2 + i;
      const int row = g * 8 + lrow;
      glds16(aq + (size_t)(m0 + row) * 256 + ka + lch * 8,
             As + g * 512 + lane * 8);
    }
#pragma unroll
    for (int i = 0; i < 6; ++i) {
      const int g = w * 6 + i;
      const int row = g * 8 + lrow;
      const ushort* gsrc = (row < 128)
          ? WsoT + (size_t)row * 512 + k0 + lch * 8
          : WawT + (size_t)(row - 128) * 512 + k0 + lch * 8;
      glds16(gsrc, Bs + g * 512 + lane * 8);
    }
  };

  STAGE(0, 0);
#pragma unroll
  for (int t = 0; t < 8; ++t) {
    const int cur = t & 1;
    if (t < 7) { STAGE(cur ^ 1, t + 1); VMWAIT(8); }
    else       { VMWAIT(0); }
    __builtin_amdgcn_s_barrier();
    {
      const ushort* Asb = (const ushort*)(smem + cur * 32768);
      const ushort* Bsb = Asb + 4096;
#pragma unroll
      for (int kk = 0; kk < 2; ++kk) {
        const short8 af = *(const short8*)
            &Asb[(w * 16 + rl) * 64 + ((kk * 4 + q2) ^ sw8) * 8];
#pragma unroll
        for (int nj = 0; nj < 12; ++nj) {
          const short8 bf = *(const short8*)
              &Bsb[(nj * 16 + rl) * 64 + ((kk * 4 + q2) ^ sw8) * 8];
          acc[nj] = __builtin_amdgcn_mfma_f32_16x16x32_bf16(af, bf, acc[nj], 0, 0, 0);
        }
      }
    }
    __builtin_amdgcn_s_barrier();
  }

  const int rbase = q2 * 4, cl = rl;
#pragma unroll
  for (int p = 0; p < 3; ++p) {
#pragma unroll
    for (int j = 0; j < 4; ++j) {
      const int nj = p * 4 + j;
      const int nl = j * 16 + cl;
      const f32x4 a = acc[nj];
      if (p < 2) {
        const float bb = b_so[p * 64 + nl];
#pragma unroll
        for (int r = 0; r < 4; ++r)
          E[w * 16 + rbase + r][nl] = a[r] + bb;
      } else {
        const float bb = b_aw[nl];
#pragma unroll
        for (int r = 0; r < 4; ++r) {
          float z = a[r] + bb;
          float zm = fmaxf(z, __shfl_xor(z, 1, 64));
          zm = fmaxf(zm, __shfl_xor(zm, 2, 64));
          float e = expf(z - zm);
          float s = e + __shfl_xor(e, 1, 64);
          s = s + __shfl_xor(s, 2, 64);
          E[w * 16 + rbase + r][nl] = e / s;
        }
      }
    }
    __syncthreads();
#pragma unroll
    for (int it = 0; it < 4; ++it) {
      const int flat = it * 256 + tid;
      const int row = flat >> 4, c4 = (flat & 15) * 4;
      const float4 vle = *(const float4*)&E[row][c4];
      if (p < 2)
        *(float4*)&so_ws[(size_t)(m0 + row) * 128 + p * 64 + c4] = vle;
      else
        *(float4*)&aw_ws[(size_t)(m0 + row) * 64 + c4] = vle;
    }
    __syncthreads();
  }
}

// v = qlo @ WvT + b_v -> bf16 head-major vt (NH, NQ, 32). N=128/block, K=256.
__global__ __launch_bounds__(256, 3) void gemm_v_k(
    const ushort* __restrict__ qlo, const ushort* __restrict__ WvT,
    const float* __restrict__ bv, ushort* __restrict__ vt) {
  __shared__ __align__(16) char smem[49152];
  ushort (*Eb)[72] = (ushort(*)[72])smem;
  f32x4 acc[8] = {};
  const int m0 = blockIdx.x * 64, n0 = blockIdx.y * 128;
  const int tid = threadIdx.x;
  const int w = tid >> 6, lane = tid & 63;
  const int rl = lane & 15, q2 = lane >> 4;
  const int sw8 = rl & 7;
  const int lrow = lane >> 3, lch = (lane & 7) ^ (lrow & 7);

  auto STAGE = [&](int buf, int t) {
    ushort* As = (ushort*)(smem + buf * 24576);
    ushort* Bs = As + 4096;
    const int k0 = t * 64;
#pragma unroll
    for (int i = 0; i < 2; ++i) {
      const int g = w * 2 + i;
      const int row = g * 8 + lrow;
      glds16(qlo + (size_t)(m0 + row) * 256 + k0 + lch * 8,
             As + g * 512 + lane * 8);
    }
#pragma unroll
    for (int i = 0; i < 4; ++i) {
      const int g = w * 4 + i;
      const int row = g * 8 + lrow;
      glds16(WvT + (size_t)(n0 + row) * 256 + k0 + lch * 8,
             Bs + g * 512 + lane * 8);
    }
  };

  STAGE(0, 0);
#pragma unroll
  for (int t = 0; t < 4; ++t) {
    const int cur = t & 1;
    if (t < 3) { STAGE(cur ^ 1, t + 1); VMWAIT(6); }
    else       { VMWAIT(0); }
    __builtin_amdgcn_s_barrier();
    {
      const ushort* Asb = (const ushort*)(smem + cur * 24576);
      const ushort* Bsb = Asb + 4096;
#pragma unroll
      for (int kk = 0; kk < 2; ++kk) {
        const short8 af = *(const short8*)
            &Asb[(w * 16 + rl) * 64 + ((kk * 4 + q2) ^ sw8) * 8];
#pragma unroll
        for (int nj = 0; nj < 8; ++nj) {
          const short8 bf = *(const short8*)
              &Bsb[(nj * 16 + rl) * 64 + ((kk * 4 + q2) ^ sw8) * 8];
          acc[nj] = __builtin_amdgcn_mfma_f32_16x16x32_bf16(af, bf, acc[nj], 0, 0, 0);
        }
      }
    }
    __builtin_amdgcn_s_barrier();
  }

  const int rbase = q2 * 4, cl = rl;
#pragma unroll
  for (int p = 0; p < 2; ++p) {
#pragma unroll
    for (int j = 0; j < 4; ++j) {
      const int nj = p * 4 + j;
      const int n = n0 + p * 64 + j * 16 + cl;
      const float bb = bv[n];
      const f32x4 a = acc[nj];
#pragma unroll
      for (int r = 0; r < 4; ++r)
        Eb[w * 16 + rbase + r][j * 16 + cl] = f2b(a[r] + bb);
    }
    __syncthreads();
#pragma unroll
    for (int hh = 0; hh < 2; ++hh) {
      const int h = (n0 + p * 64) / 32 + hh;
#pragma unroll
      for (int it = 0; it < 2; ++it) {
        const int flat = it * 256 + tid;
        const int row = flat >> 3, d4 = (flat & 7) * 4;
        *(ushort4*)&vt[((size_t)h * NQc + m0 + row) * 32 + d4] =
            *(const ushort4*)&Eb[row][hh * 32 + d4];
      }
    }
    __syncthreads();
  }
}

// ---------------------------------------------------------------------------
// gemm_front: soaw + v merged into ONE launch (used only when workspace
// permits non-aliased vt). bid<1250: v path (m0=(bid>>1)*64, n0=(bid&1)*128);
// bid>=1250: soaw path (m0=(bid-1250)*64). Bodies identical to the separate
// kernels above; shared 64KB smem -> 2 blocks/CU both paths.
// ---------------------------------------------------------------------------
__global__ __launch_bounds__(256, 2) void gemm_front(
    const ushort* __restrict__ qlo, const ushort* __restrict__ qhi,
    const ushort* __restrict__ WvT, const ushort* __restrict__ WsoT,
    const ushort* __restrict__ WawT,
    const float* __restrict__ bv, const float* __restrict__ b_so,
    const float* __restrict__ b_aw,
    ushort* __restrict__ vt, float* __restrict__ so_ws,
    float* __restrict__ aw_ws) {
  __shared__ __align__(16) char smem[65536];
  const int tid = threadIdx.x;
  const int w = tid >> 6, lane = tid & 63;
  const int rl = lane & 15, q2 = lane >> 4;
  const int sw8 = rl & 7;
  const int lrow = lane >> 3, lch = (lane & 7) ^ (lrow & 7);
  const int bid = blockIdx.x;

  if (bid < 1250) {
    // ================= v path =================
    ushort (*Eb)[72] = (ushort(*)[72])smem;
    f32x4 acc[8] = {};
    const int m0 = (bid >> 1) * 64, n0 = (bid & 1) * 128;

    auto STAGE = [&](int buf, int t) {
      ushort* As = (ushort*)(smem + buf * 24576);
      ushort* Bs = As + 4096;
      const int k0 = t * 64;
#pragma unroll
      for (int i = 0; i < 2; ++i) {
        const int g = w * 2 + i;
        const int row = g * 8 + lrow;
        glds16(qlo + (size_t)(m0 + row) * 256 + k0 + lch * 8,
               As + g * 512 + lane * 8);
      }
#pragma unroll
      for (int i = 0; i < 4; ++i) {
        const int g = w * 4 + i;
        const int row = g * 8 + lrow;
        glds16(WvT + (size_t)(n0 + row) * 256 + k0 + lch * 8,
               Bs + g * 512 + lane * 8);
      }
    };

    STAGE(0, 0);
#pragma unroll
    for (int t = 0; t < 4; ++t) {
      const int cur = t & 1;
      if (t < 3) { STAGE(cur ^ 1, t + 1); VMWAIT(6); }
      else       { VMWAIT(0); }
      __builtin_amdgcn_s_barrier();
      {
        const ushort* Asb = (const ushort*)(smem + cur * 24576);
        const ushort* Bsb = Asb + 4096;
#pragma unroll
        for (int kk = 0; kk < 2; ++kk) {
          const short8 af = *(const short8*)
              &Asb[(w * 16 + rl) * 64 + ((kk * 4 + q2) ^ sw8) * 8];
#pragma unroll
          for (int nj = 0; nj < 8; ++nj) {
            const short8 bf = *(const short8*)
                &Bsb[(nj * 16 + rl) * 64 + ((kk * 4 + q2) ^ sw8) * 8];
            acc[nj] = __builtin_amdgcn_mfma_f32_16x16x32_bf16(af, bf, acc[nj], 0, 0, 0);
          }
        }
      }
      __builtin_amdgcn_s_barrier();
    }

    const int rbase = q2 * 4, cl = rl;
#pragma unroll
    for (int p = 0; p < 2; ++p) {
#pragma unroll
      for (int j = 0; j < 4; ++j) {
        const int nj = p * 4 + j;
        const int n = n0 + p * 64 + j * 16 + cl;
        const float bb = bv[n];
        const f32x4 a = acc[nj];
#pragma unroll
        for (int r = 0; r < 4; ++r)
          Eb[w * 16 + rbase + r][j * 16 + cl] = f2b(a[r] + bb);
      }
      __syncthreads();
#pragma unroll
      for (int hh = 0; hh < 2; ++hh) {
        const int h = (n0 + p * 64) / 32 + hh;
#pragma unroll
        for (int it = 0; it < 2; ++it) {
          const int flat = it * 256 + tid;
          const int row = flat >> 3, d4 = (flat & 7) * 4;
          *(ushort4*)&vt[((size_t)h * NQc + m0 + row) * 32 + d4] =
              *(const ushort4*)&Eb[row][hh * 32 + d4];
        }
      }
      __syncthreads();
    }
  } else {
    // ================= soaw path =================
    float (*E)[68] = (float(*)[68])smem;
    f32x4 acc[12] = {};
    const int m0 = (bid - 1250) * 64;

    auto STAGE = [&](int buf, int t) {
      ushort* As = (ushort*)(smem + buf * 32768);
      ushort* Bs = As + 4096;
      const int k0 = t * 64;
      const ushort* aq = (k0 < 256) ? qlo : qhi;
      const int ka = k0 & 255;
#pragma unroll
      for (int i = 0; i < 2; ++i) {
        const int g = w * 2 + i;
        const int row = g * 8 + lrow;
        glds16(aq + (size_t)(m0 + row) * 256 + ka + lch * 8,
               As + g * 512 + lane * 8);
      }
#pragma unroll
      for (int i = 0; i < 6; ++i) {
        const int g = w * 6 + i;
        const int row = g * 8 + lrow;
        const ushort* gsrc = (row < 128)
            ? WsoT + (size_t)row * 512 + k0 + lch * 8
            : WawT + (size_t)(row - 128) * 512 + k0 + lch * 8;
        glds16(gsrc, Bs + g * 512 + lane * 8);
      }
    };

    STAGE(0, 0);
#pragma unroll
    for (int t = 0; t < 8; ++t) {
      const int cur = t & 1;
      if (t < 7) { STAGE(cur ^ 1, t + 1); VMWAIT(8); }
      else       { VMWAIT(0); }
      __builtin_amdgcn_s_barrier();
      {
        const ushort* Asb = (const ushort*)(smem + cur * 32768);
        const ushort* Bsb = Asb + 4096;
#pragma unroll
        for (int kk = 0; kk < 2; ++kk) {
          const short8 af = *(const short8*)
              &Asb[(w * 16 + rl) * 64 + ((kk * 4 + q2) ^ sw8) * 8];
#pragma unroll
          for (int nj = 0; nj < 12; ++nj) {
            const short8 bf = *(const short8*)
                &Bsb[(nj * 16 + rl) * 64 + ((kk * 4 + q2) ^ sw8) * 8];
            acc[nj] = __builtin_amdgcn_mfma_f32_16x16x32_bf16(af, bf, acc[nj], 0, 0, 0);
          }
        }
      }
      __builtin_amdgcn_s_barrier();
    }

    const int rbase = q2 * 4, cl = rl;
#pragma unroll
    for (int p = 0; p < 3; ++p) {
#pragma unroll
      for (int j = 0; j < 4; ++j) {
        const int nj = p * 4 + j;
        const int nl = j * 16 + cl;
        const f32x4 a = acc[nj];
        if (p < 2) {
          const float bb = b_so[p * 64 + nl];
#pragma unroll
          for (int r = 0; r < 4; ++r)
            E[w * 16 + rbase + r][nl] = a[r] + bb;
        } else {
          const float bb = b_aw[nl];
#pragma unroll
          for (int r = 0; r < 4; ++r) {
            float z = a[r] + bb;
            float zm = fmaxf(z, __shfl_xor(z, 1, 64));
            zm = fmaxf(zm, __shfl_xor(zm, 2, 64));
            float e = expf(z - zm);
            float s = e + __shfl_xor(e, 1, 64);
            s = s + __shfl_xor(s, 2, 64);
            E[w * 16 + rbase + r][nl] = e / s;
          }
        }
      }
      __syncthreads();
#pragma unroll
      for (int it = 0; it < 4; ++it) {
        const int flat = it * 256 + tid;
        const int row = flat >> 4, c4 = (flat & 15) * 4;
        const float4 vle = *(const float4*)&E[row][c4];
        if (p < 2)
          *(float4*)&so_ws[(size_t)(m0 + row) * 128 + p * 64 + c4] = vle;
        else
          *(float4*)&aw_ws[(size_t)(m0 + row) * 64 + c4] = vle;
      }
      __syncthreads();
    }
  }
}

// out = out_pre @ WoT + b_o -> fp32. N=128/block, K=256. Counted-vmcnt dbuf.
__global__ __launch_bounds__(256, 3) void gemm_o_k(
    const ushort* __restrict__ Ap, const ushort* __restrict__ WoT,
    const float* __restrict__ bo, float* __restrict__ out) {
  __shared__ __align__(16) char smem[49152];
  float (*E)[68] = (float(*)[68])smem;
  f32x4 acc[8] = {};
  const int m0 = blockIdx.x * 64, n0 = blockIdx.y * 128;
  const int tid = threadIdx.x;
  const int w = tid >> 6, lane = tid & 63;
  const int rl = lane & 15, q2 = lane >> 4;
  const int sw8 = rl & 7;
  const int lrow = lane >> 3, lch = (lane & 7) ^ (lrow & 7);

  auto STAGE = [&](int buf, int t) {
    ushort* As = (ushort*)(smem + buf * 24576);
    ushort* Bs = As + 4096;
    const int k0 = t * 64;
#pragma unroll
    for (int i = 0; i < 2; ++i) {
      const int g = w * 2 + i;
      const int row = g * 8 + lrow;
      glds16(Ap + (size_t)(m0 + row) * 256 + k0 + lch * 8,
             As + g * 512 + lane * 8);
    }
#pragma unroll
    for (int i = 0; i < 4; ++i) {
      const int g = w * 4 + i;
      const int row = g * 8 + lrow;
      glds16(WoT + (size_t)(n0 + row) * 256 + k0 + lch * 8,
             Bs + g * 512 + lane * 8);
    }
  };

  STAGE(0, 0);
#pragma unroll
  for (int t = 0; t < 4; ++t) {
    const int cur = t & 1;
    if (t < 3) { STAGE(cur ^ 1, t + 1); VMWAIT(6); }
    else       { VMWAIT(0); }
    __builtin_amdgcn_s_barrier();
    {
      const ushort* Asb = (const ushort*)(smem + cur * 24576);
      const ushort* Bsb = Asb + 4096;
#pragma unroll
      for (int kk = 0; kk < 2; ++kk) {
        const short8 af = *(const short8*)
            &Asb[(w * 16 + rl) * 64 + ((kk * 4 + q2) ^ sw8) * 8];
#pragma unroll
        for (int nj = 0; nj < 8; ++nj) {
          const short8 bf = *(const short8*)
              &Bsb[(nj * 16 + rl) * 64 + ((kk * 4 + q2) ^ sw8) * 8];
          acc[nj] = __builtin_amdgcn_mfma_f32_16x16x32_bf16(af, bf, acc[nj], 0, 0, 0);
        }
      }
    }
    __builtin_amdgcn_s_barrier();
  }

  const int rbase = q2 * 4, cl = rl;
#pragma unroll
  for (int p = 0; p < 2; ++p) {
#pragma unroll
    for (int j = 0; j < 4; ++j) {
      const int nj = p * 4 + j;
      const int n = n0 + p * 64 + j * 16 + cl;
      const float bb = bo[n];
      const f32x4 a = acc[nj];
#pragma unroll
      for (int r = 0; r < 4; ++r)
        E[w * 16 + rbase + r][j * 16 + cl] = a[r] + bb;
    }
    __syncthreads();
#pragma unroll
    for (int it = 0; it < 4; ++it) {
      const int flat = it * 256 + tid;
      const int row = flat >> 4, c4 = (flat & 15) * 4;
      *(float4*)&out[(size_t)(m0 + row) * 256 + n0 + p * 64 + c4] =
          *(const float4*)&E[row][c4];
    }
    __syncthreads();
  }
}

// ---------------------------------------------------------------------------
// Deformable sampling: block = one head x 32 queries; head = blockIdx.x & 7
// pins each head's 2.56 MB vt slice to one XCD's L2. (R4 version, unchanged)
// ---------------------------------------------------------------------------
__global__ __launch_bounds__(256) void sample_kernel(
    const ushort* __restrict__ vt,    // (NH, NQ, 32) bf16
    const float* __restrict__ so_ws,  // (NQ, 128)
    const float* __restrict__ aw_ws,  // (NQ, 64)
    const float* __restrict__ refp,   // (NQ, 2)
    ushort* __restrict__ out_pre)     // (NQ, 256) bf16
{
  __shared__ int2   offs[32][9];
  __shared__ float2 wts2[32][9][2];
  const int h  = blockIdx.x & 7;
  const int m0 = (blockIdx.x >> 3) * 32;
  const int tid = threadIdx.x;

  {
    const int j  = tid & 7;
    const int qi = tid >> 3;
    const int m  = m0 + qi;
    const int c  = h * 8 + j;
    const float sx  = so_ws[(size_t)m * 128 + c * 2 + 0];
    const float sy  = so_ws[(size_t)m * 128 + c * 2 + 1];
    const float wgt = 0.5f * aw_ws[(size_t)m * 64 + c];
    const float x = refp[m * 2 + 0] * (float)Wc + sx - 0.5f;
    const float y = refp[m * 2 + 1] * (float)Hc + sy - 0.5f;
    const float x0f = floorf(x), y0f = floorf(y);
    const int x0 = (int)x0f, y0 = (int)y0f;
    const int x1 = x0 + 1, y1 = y0 + 1;
    const float wx1 = x - x0f, wx0 = 1.0f - wx1;
    const float wy1 = y - y0f, wy0 = 1.0f - wy1;
    const float wx0v = (x0 >= 0 && x0 < Wc) ? wx0 : 0.0f;
    const float wx1v = (x1 >= 0 && x1 < Wc) ? wx1 : 0.0f;
    const float wy0v = ((y0 >= 0 && y0 < Hc) ? wy0 : 0.0f) * wgt;
    const float wy1v = ((y1 >= 0 && y1 < Hc) ? wy1 : 0.0f) * wgt;
    const int bx = min(max(x0, 0), Wc - 2);
    const float wl = (bx == x0) ? wx0v : ((bx == x1) ? wx1v : 0.0f);
    const float wr = (bx + 1 == x1) ? wx1v : ((bx + 1 == x0) ? wx0v : 0.0f);
    const int cy0 = min(max(y0, 0), Hc - 1);
    const int cy1 = min(max(y1, 0), Hc - 1);
    offs[qi][j] = make_int2((cy0 * Wc + bx) * 64, (cy1 * Wc + bx) * 64);
    wts2[qi][j][0] = make_float2(wl * wy0v, wl * wy1v);
    wts2[qi][j][1] = make_float2(wr * wy0v, wr * wy1v);
  }
  __syncthreads();

  const int qi = tid >> 3;
  const int ld = tid & 7;
  const int m  = m0 + qi;
  const int hf = ld >> 2;
  const char* __restrict__ vb =
      (const char*)(vt + (size_t)h * NQc * 32) + (uint)(ld * 16);

  uint4 raw[16];
#pragma unroll
  for (int j = 0; j < 8; ++j) {
    const int2 oo = offs[qi][j];
    raw[2 * j]     = *(const uint4*)(vb + (uint)oo.x);
    raw[2 * j + 1] = *(const uint4*)(vb + (uint)oo.y);
  }
  __builtin_amdgcn_sched_barrier(0);

  f32x2 acc0 = {0.0f, 0.0f}, acc1 = {0.0f, 0.0f};
  f32x2 acc2 = {0.0f, 0.0f}, acc3 = {0.0f, 0.0f};

#pragma unroll
  for (int j = 0; j < 8; ++j) {
    const float2 wp = wts2[qi][j][hf];
#pragma unroll
    for (int r = 0; r < 2; ++r) {
      const uint4 rawv = raw[2 * j + r];
      const float w = (r == 0) ? wp.x : wp.y;
      const f32x2 wv = {w, w};
      f32x2 v0, v1, v2, v3;
      v0.x = __uint_as_float(rawv.x << 16);
      v0.y = __uint_as_float(rawv.x & 0xFFFF0000u);
      v1.x = __uint_as_float(rawv.y << 16);
      v1.y = __uint_as_float(rawv.y & 0xFFFF0000u);
      v2.x = __uint_as_float(rawv.z << 16);
      v2.y = __uint_as_float(rawv.z & 0xFFFF0000u);
      v3.x = __uint_as_float(rawv.w << 16);
      v3.y = __uint_as_float(rawv.w & 0xFFFF0000u);
#if __has_builtin(__builtin_elementwise_fma)
      acc0 = __builtin_elementwise_fma(wv, v0, acc0);
      acc1 = __builtin_elementwise_fma(wv, v1, acc1);
      acc2 = __builtin_elementwise_fma(wv, v2, acc2);
      acc3 = __builtin_elementwise_fma(wv, v3, acc3);
#else
      acc0.x = fmaf(w, v0.x, acc0.x); acc0.y = fmaf(w, v0.y, acc0.y);
      acc1.x = fmaf(w, v1.x, acc1.x); acc1.y = fmaf(w, v1.y, acc1.y);
      acc2.x = fmaf(w, v2.x, acc2.x); acc2.y = fmaf(w, v2.y, acc2.y);
      acc3.x = fmaf(w, v3.x, acc3.x); acc3.y = fmaf(w, v3.y, acc3.y);
#endif
    }
  }

  float a[8] = {acc0.x, acc0.y, acc1.x, acc1.y,
                acc2.x, acc2.y, acc3.x, acc3.y};
#pragma unroll
  for (int k = 0; k < 8; ++k) a[k] += __shfl_xor(a[k], 4, 64);

  if (hf == 0) {
    ushort rr[8];
#pragma unroll
    for (int k = 0; k < 8; ++k) rr[k] = f2b(a[k]);
    *(uint4*)&out_pre[(size_t)m * 256 + h * 32 + ld * 8] = *(const uint4*)rr;
  }
}

extern "C" void kernel_launch(void* const* d_in, const int* in_sizes, int n_in,
                              void* d_out, int out_size, void* d_ws, size_t ws_size,
                              hipStream_t stream) {
  const float* query     = (const float*)d_in[0];
  const float* query_pos = (const float*)d_in[1];
  const float* refp      = (const float*)d_in[2];
  const float* W_so      = (const float*)d_in[3];
  const float* b_so      = (const float*)d_in[4];
  const float* W_aw      = (const float*)d_in[5];
  const float* b_aw      = (const float*)d_in[6];
  const float* W_v       = (const float*)d_in[7];
  const float* b_v       = (const float*)d_in[8];
  const float* W_o       = (const float*)d_in[9];
  const float* b_o       = (const float*)d_in[10];
  float* out = (float*)d_out;
  char* base = (char*)d_ws;

  if (ws_size >= (size_t)92618752) {
    // ---- big layout: no vt/qhi aliasing -> merged front kernel ----
    ushort* qlo     = (ushort*)base;                     // 20,480,000
    ushort* qhi     = (ushort*)(base + 20480000);        // 20,480,000
    ushort* vt      = (ushort*)(base + 40960000);        // 20,480,000
    float*  so_ws   = (float*)(base + 61440000);         // 20,480,000
    float*  aw_ws   = (float*)(base + 81920000);         // 10,240,000
    ushort* out_pre = (ushort*)base;                     // alias qlo (dead)
    ushort* WvT     = (ushort*)(base + 92160000);
    ushort* WoT     = WvT + 65536;
    ushort* WsoT    = WoT + 65536;
    ushort* WawT    = WsoT + 65536;

    prep_all<<<5896, 256, 0, stream>>>(query, query_pos, W_v, W_o, W_so, W_aw,
                                       qlo, qhi, WvT, WoT, WsoT, WawT);
    gemm_front<<<1875, 256, 0, stream>>>(qlo, qhi, WvT, WsoT, WawT,
                                         b_v, b_so, b_aw, vt, so_ws, aw_ws);
    sample_kernel<<<10000, 256, 0, stream>>>(vt, so_ws, aw_ws, refp, out_pre);
    gemm_o_k<<<dim3(625, 2), 256, 0, stream>>>(out_pre, WoT, b_o, out);
  } else {
    // ---- R4 layout (aliased, 72.1 MB) and schedule ----
    ushort* qlo     = (ushort*)base;
    ushort* qhi     = (ushort*)(base + 20480000);
    ushort* vt      = (ushort*)(base + 20480000);        // alias qhi
    ushort* out_pre = (ushort*)base;                     // alias qlo
    float*  so_ws   = (float*)(base + 40960000);
    float*  aw_ws   = (float*)(base + 61440000);
    ushort* WvT     = (ushort*)(base + 71680000);
    ushort* WoT     = WvT + 65536;
    ushort* WsoT    = WoT + 65536;
    ushort* WawT    = WsoT + 65536;

    prep_all<<<5896, 256, 0, stream>>>(query, query_pos, W_v, W_o, W_so, W_aw,
                                       qlo, qhi, WvT, WoT, WsoT, WawT);
    gemm_soaw_k<<<625, 256, 0, stream>>>(qlo, qhi, WsoT, WawT,
                                         b_so, b_aw, so_ws, aw_ws);
    gemm_v_k<<<dim3(625, 2), 256, 0, stream>>>(qlo, WvT, b_v, vt);
    sample_kernel<<<10000, 256, 0, stream>>>(vt, so_ws, aw_ws, refp, out_pre);
    gemm_o_k<<<dim3(625, 2), 256, 0, stream>>>(out_pre, WoT, b_o, out);
  }
}